// Round 1
// baseline (2086.511 us; speedup 1.0000x reference)
//
#include <hip/hip_runtime.h>

#define BQ 4
#define NH 8
#define NTOK 8448
#define NLAT 256
#define NPTS 8192
#define CDIM 512
#define HD 64
#define SCALE 0.125f

static __device__ __forceinline__ float4 ld4(const float* p) { return *(const float4*)p; }

// ---------------- K1: qkv = x @ w_qkv^T, scatter to q,k,v laid out [b][h][n][d]
__global__ __launch_bounds__(256) void qkv_gemm(const float* __restrict__ x,
                                                const float* __restrict__ w,
                                                float* __restrict__ qo,
                                                float* __restrict__ ko,
                                                float* __restrict__ vo) {
  __shared__ float As[16][132];
  __shared__ float Bs[16][132];
  const int m0 = blockIdx.y * 128;
  const int j0 = blockIdx.x * 128;
  const int t  = threadIdx.x;
  const int tx = t & 15, ty = t >> 4;
  float acc[8][8] = {};
  for (int k0 = 0; k0 < CDIM; k0 += 16) {
#pragma unroll
    for (int i = 0; i < 2; ++i) {
      const int fl  = t + i * 256;
      const int row = fl >> 2;
      const int kq  = (fl & 3) << 2;
      float4 av = ld4(&x[(size_t)(m0 + row) * CDIM + k0 + kq]);
      As[kq + 0][row] = av.x; As[kq + 1][row] = av.y;
      As[kq + 2][row] = av.z; As[kq + 3][row] = av.w;
      float4 bv = ld4(&w[(size_t)(j0 + row) * CDIM + k0 + kq]);
      Bs[kq + 0][row] = bv.x; Bs[kq + 1][row] = bv.y;
      Bs[kq + 2][row] = bv.z; Bs[kq + 3][row] = bv.w;
    }
    __syncthreads();
#pragma unroll
    for (int kk = 0; kk < 16; ++kk) {
      float4 a0 = ld4(&As[kk][ty * 4]);
      float4 a1 = ld4(&As[kk][64 + ty * 4]);
      float4 b0 = ld4(&Bs[kk][tx * 4]);
      float4 b1 = ld4(&Bs[kk][64 + tx * 4]);
      float av[8] = {a0.x, a0.y, a0.z, a0.w, a1.x, a1.y, a1.z, a1.w};
      float bv[8] = {b0.x, b0.y, b0.z, b0.w, b1.x, b1.y, b1.z, b1.w};
#pragma unroll
      for (int i = 0; i < 8; ++i)
#pragma unroll
        for (int j = 0; j < 8; ++j) acc[i][j] += av[i] * bv[j];
    }
    __syncthreads();
  }
#pragma unroll
  for (int i = 0; i < 8; ++i) {
    const int row = m0 + ((i < 4) ? (ty * 4 + i) : (64 + ty * 4 + (i - 4)));
    const int b = row / NTOK, n = row % NTOK;
#pragma unroll
    for (int jh = 0; jh < 2; ++jh) {
      const int j = j0 + jh * 64 + tx * 4;
      const int s = j >> 9;
      const int h = (j >> 6) & 7;
      const int d = j & 63;
      float* dst = (s == 0) ? qo : ((s == 1) ? ko : vo);
      float4 val = make_float4(acc[i][jh * 4 + 0], acc[i][jh * 4 + 1],
                               acc[i][jh * 4 + 2], acc[i][jh * 4 + 3]);
      *(float4*)&dst[(((size_t)b * NH + h) * NTOK + n) * HD + d] = val;
    }
  }
}

// ---------------- K2: points attention (cross vs 256 latents + self column), online softmax
__global__ __launch_bounds__(512) void points_attn(const float* __restrict__ q,
                                                   const float* __restrict__ k,
                                                   const float* __restrict__ v,
                                                   float* __restrict__ ao,
                                                   float* __restrict__ md) {
  __shared__ float sk[256 * 64];
  __shared__ float sv[256 * 64];
  const int bid = blockIdx.x;
  const int bh = bid >> 4;      // b*8+h
  const int pt = bid & 15;
  const int t  = threadIdx.x;
  const size_t base = (size_t)bh * NTOK * HD;   // token 0 of this (b,h)
#pragma unroll
  for (int i = 0; i < 8; ++i) {
    const int c = t + i * 512;                  // float4 index in [0,4096)
    *(float4*)&sk[c * 4] = ld4(&k[base + (size_t)c * 4]);
    *(float4*)&sv[c * 4] = ld4(&v[base + (size_t)c * 4]);
  }
  const int p = pt * 512 + t;
  const size_t nb = base + (size_t)(NLAT + p) * HD;
  float qr[64];
  float sself = 0.f;
#pragma unroll
  for (int i = 0; i < 16; ++i) {
    float4 qv = ld4(&q[nb + i * 4]);
    float4 kv = ld4(&k[nb + i * 4]);
    qr[i * 4 + 0] = qv.x; qr[i * 4 + 1] = qv.y; qr[i * 4 + 2] = qv.z; qr[i * 4 + 3] = qv.w;
    sself += qv.x * kv.x + qv.y * kv.y + qv.z * kv.z + qv.w * kv.w;
  }
  sself *= SCALE;
  float acc[64];
#pragma unroll
  for (int i = 0; i < 16; ++i) {
    float4 vv = ld4(&v[nb + i * 4]);
    acc[i * 4 + 0] = vv.x; acc[i * 4 + 1] = vv.y; acc[i * 4 + 2] = vv.z; acc[i * 4 + 3] = vv.w;
  }
  float m = sself, ssum = 1.f;
  __syncthreads();
  for (int l = 0; l < 256; ++l) {
    const float* kr = &sk[l * 64];
    float s0 = 0.f, s1 = 0.f, s2 = 0.f, s3 = 0.f;
#pragma unroll
    for (int d = 0; d < 64; d += 4) {
      s0 += qr[d + 0] * kr[d + 0];
      s1 += qr[d + 1] * kr[d + 1];
      s2 += qr[d + 2] * kr[d + 2];
      s3 += qr[d + 3] * kr[d + 3];
    }
    float s = ((s0 + s1) + (s2 + s3)) * SCALE;
    const float* vr = &sv[l * 64];
    if (s <= m) {
      float pw = __expf(s - m);
      ssum += pw;
#pragma unroll
      for (int d = 0; d < 64; ++d) acc[d] += pw * vr[d];
    } else {
      float c = __expf(m - s);
      m = s;
      ssum = ssum * c + 1.f;
#pragma unroll
      for (int d = 0; d < 64; ++d) acc[d] = acc[d] * c + vr[d];
    }
  }
  const float inv = 1.f / ssum;
  const int b = bh >> 3, h = bh & 7;
  const int n = NLAT + p;
  const size_t ob = ((size_t)b * NTOK + n) * CDIM + h * HD;
#pragma unroll
  for (int i = 0; i < 16; ++i) {
    float4 ov = make_float4(acc[i * 4 + 0] * inv, acc[i * 4 + 1] * inv,
                            acc[i * 4 + 2] * inv, acc[i * 4 + 3] * inv);
    *(float4*)&ao[ob + i * 4] = ov;
  }
  md[((size_t)bh * NPTS + p) * 2 + 0] = m;
  md[((size_t)bh * NPTS + p) * 2 + 1] = ssum;
}

// ---------------- K3: latent self-attention (256x256 per (b,h))
__global__ __launch_bounds__(256) void latent_attn(const float* __restrict__ q,
                                                   const float* __restrict__ k,
                                                   const float* __restrict__ v,
                                                   float* __restrict__ ao) {
  __shared__ float sA[64 * 257];   // k staging (flat, first 16384) then probs (pitch 257)
  __shared__ float sv[256 * 64];
  __shared__ float sred[256];
  const int bid = blockIdx.x;
  const int bh = bid >> 2, rt = bid & 3;
  const int t = threadIdx.x;
  const int rl = t & 63, g = t >> 6;
  const size_t base = (size_t)bh * NTOK * HD;
#pragma unroll
  for (int i = 0; i < 16; ++i) {
    const int c = t + i * 256;     // float4 index in [0,4096)
    *(float4*)&sA[c * 4] = ld4(&k[base + (size_t)c * 4]);
    *(float4*)&sv[c * 4] = ld4(&v[base + (size_t)c * 4]);
  }
  const int r = rt * 64 + rl;
  float qr[64];
#pragma unroll
  for (int i = 0; i < 16; ++i) {
    float4 qv = ld4(&q[base + (size_t)r * HD + i * 4]);
    qr[i * 4 + 0] = qv.x; qr[i * 4 + 1] = qv.y; qr[i * 4 + 2] = qv.z; qr[i * 4 + 3] = qv.w;
  }
  __syncthreads();
  float sc[64];
  float mymax = -1e30f;
#pragma unroll
  for (int ll = 0; ll < 64; ++ll) {
    const float* kr = &sA[(g * 64 + ll) * 64];
    float s0 = 0.f, s1 = 0.f, s2 = 0.f, s3 = 0.f;
#pragma unroll
    for (int d = 0; d < 64; d += 4) {
      s0 += qr[d + 0] * kr[d + 0];
      s1 += qr[d + 1] * kr[d + 1];
      s2 += qr[d + 2] * kr[d + 2];
      s3 += qr[d + 3] * kr[d + 3];
    }
    sc[ll] = ((s0 + s1) + (s2 + s3)) * SCALE;
    mymax = fmaxf(mymax, sc[ll]);
  }
  __syncthreads();               // all k reads complete
  sred[rl * 4 + g] = mymax;
  __syncthreads();
  const float M = fmaxf(fmaxf(sred[rl * 4 + 0], sred[rl * 4 + 1]),
                        fmaxf(sred[rl * 4 + 2], sred[rl * 4 + 3]));
  __syncthreads();               // M reads done; sred reusable, sA writable
  float ps = 0.f;
#pragma unroll
  for (int ll = 0; ll < 64; ++ll) {
    float e = __expf(sc[ll] - M);
    ps += e;
    sA[rl * 257 + g * 64 + ll] = e;
  }
  sred[rl * 4 + g] = ps;
  __syncthreads();
  const float S = sred[rl * 4 + 0] + sred[rl * 4 + 1] + sred[rl * 4 + 2] + sred[rl * 4 + 3];
  const float inv = 1.f / S;
  float pacc[16] = {};
  for (int l = 0; l < 256; ++l) {
    const float pw = sA[rl * 257 + l];
    const float* vr = &sv[l * 64 + g * 16];
#pragma unroll
    for (int dd = 0; dd < 16; ++dd) pacc[dd] += pw * vr[dd];
  }
  const int b = bh >> 3, h = bh & 7;
  const size_t ob = ((size_t)b * NTOK + r) * CDIM + h * HD + g * 16;
#pragma unroll
  for (int i = 0; i < 4; ++i) {
    float4 ov = make_float4(pacc[i * 4 + 0] * inv, pacc[i * 4 + 1] * inv,
                            pacc[i * 4 + 2] * inv, pacc[i * 4 + 3] * inv);
    *(float4*)&ao[ob + i * 4] = ov;
  }
}

// ---------------- K4: attn_mean = (1/8) sum_h softmax probs (recompute scores, use stored m/denom)
__global__ __launch_bounds__(256) void attn_mean_k(const float* __restrict__ q,
                                                   const float* __restrict__ k,
                                                   const float* __restrict__ md,
                                                   float* __restrict__ out1) {
  __shared__ float kq[256 * 65];
  __shared__ float sq[32 * 65];
  __shared__ float smax[32], sinv[32];
  const int bid = blockIdx.x;
  const int b = bid >> 8;
  const int pt = bid & 255;
  const int p0 = pt * 32;
  const int t = threadIdx.x;
  const int lc = t & 7, pl = t >> 3;
  float acc[32] = {};
  for (int h = 0; h < NH; ++h) {
    const int bh = b * NH + h;
    const size_t base = (size_t)bh * NTOK * HD;
#pragma unroll
    for (int i = 0; i < 16; ++i) {
      const int c = t + i * 256;            // float4 idx [0,4096)
      const int l = c >> 4, d4 = (c & 15) * 4;
      float4 kv = ld4(&k[base + (size_t)c * 4]);
      kq[l * 65 + d4 + 0] = kv.x; kq[l * 65 + d4 + 1] = kv.y;
      kq[l * 65 + d4 + 2] = kv.z; kq[l * 65 + d4 + 3] = kv.w;
    }
#pragma unroll
    for (int i = 0; i < 2; ++i) {
      const int c = t + i * 256;            // float4 idx [0,512)
      const int r = c >> 4, d4 = (c & 15) * 4;
      float4 qv = ld4(&q[base + (size_t)(NLAT + p0 + r) * HD + d4]);
      sq[r * 65 + d4 + 0] = qv.x; sq[r * 65 + d4 + 1] = qv.y;
      sq[r * 65 + d4 + 2] = qv.z; sq[r * 65 + d4 + 3] = qv.w;
    }
    if (t < 32) {
      smax[t] = md[((size_t)bh * NPTS + p0 + t) * 2 + 0];
      sinv[t] = 1.f / md[((size_t)bh * NPTS + p0 + t) * 2 + 1];
    }
    __syncthreads();
    const float* qrow = &sq[pl * 65];
    const float mm = smax[pl];
    const float iv = sinv[pl];
#pragma unroll
    for (int ll = 0; ll < 32; ++ll) {
      const int l = lc + ll * 8;
      const float* kr = &kq[l * 65];
      float s0 = 0.f, s1 = 0.f, s2 = 0.f, s3 = 0.f;
#pragma unroll
      for (int d = 0; d < 64; d += 4) {
        s0 += qrow[d + 0] * kr[d + 0];
        s1 += qrow[d + 1] * kr[d + 1];
        s2 += qrow[d + 2] * kr[d + 2];
        s3 += qrow[d + 3] * kr[d + 3];
      }
      float s = ((s0 + s1) + (s2 + s3)) * SCALE;
      acc[ll] += __expf(s - mm) * iv;
    }
    __syncthreads();
  }
  const size_t ob = ((size_t)b * NPTS + p0 + pl) * NLAT;
#pragma unroll
  for (int ll = 0; ll < 32; ++ll) out1[ob + lc + ll * 8] = acc[ll] * 0.125f;
}

// ---------------- K5: output = ao @ w_proj^T + b_proj
__global__ __launch_bounds__(256) void proj_gemm(const float* __restrict__ A,
                                                 const float* __restrict__ w,
                                                 const float* __restrict__ bias,
                                                 float* __restrict__ out) {
  __shared__ float As[16][132];
  __shared__ float Bs[16][132];
  const int m0 = blockIdx.y * 128;
  const int j0 = blockIdx.x * 128;
  const int t  = threadIdx.x;
  const int tx = t & 15, ty = t >> 4;
  float acc[8][8] = {};
  for (int k0 = 0; k0 < CDIM; k0 += 16) {
#pragma unroll
    for (int i = 0; i < 2; ++i) {
      const int fl  = t + i * 256;
      const int row = fl >> 2;
      const int kq  = (fl & 3) << 2;
      float4 av = ld4(&A[(size_t)(m0 + row) * CDIM + k0 + kq]);
      As[kq + 0][row] = av.x; As[kq + 1][row] = av.y;
      As[kq + 2][row] = av.z; As[kq + 3][row] = av.w;
      float4 bv = ld4(&w[(size_t)(j0 + row) * CDIM + k0 + kq]);
      Bs[kq + 0][row] = bv.x; Bs[kq + 1][row] = bv.y;
      Bs[kq + 2][row] = bv.z; Bs[kq + 3][row] = bv.w;
    }
    __syncthreads();
#pragma unroll
    for (int kk = 0; kk < 16; ++kk) {
      float4 a0 = ld4(&As[kk][ty * 4]);
      float4 a1 = ld4(&As[kk][64 + ty * 4]);
      float4 b0 = ld4(&Bs[kk][tx * 4]);
      float4 b1 = ld4(&Bs[kk][64 + tx * 4]);
      float av[8] = {a0.x, a0.y, a0.z, a0.w, a1.x, a1.y, a1.z, a1.w};
      float bv[8] = {b0.x, b0.y, b0.z, b0.w, b1.x, b1.y, b1.z, b1.w};
#pragma unroll
      for (int i = 0; i < 8; ++i)
#pragma unroll
        for (int j = 0; j < 8; ++j) acc[i][j] += av[i] * bv[j];
    }
    __syncthreads();
  }
#pragma unroll
  for (int i = 0; i < 8; ++i) {
    const int row = m0 + ((i < 4) ? (ty * 4 + i) : (64 + ty * 4 + (i - 4)));
#pragma unroll
    for (int jh = 0; jh < 2; ++jh) {
      const int j = j0 + jh * 64 + tx * 4;
      float4 bb = ld4(&bias[j]);
      float4 val = make_float4(acc[i][jh * 4 + 0] + bb.x, acc[i][jh * 4 + 1] + bb.y,
                               acc[i][jh * 4 + 2] + bb.z, acc[i][jh * 4 + 3] + bb.w);
      *(float4*)&out[(size_t)row * CDIM + j] = val;
    }
  }
}

extern "C" void kernel_launch(void* const* d_in, const int* in_sizes, int n_in,
                              void* d_out, int out_size, void* d_ws, size_t ws_size,
                              hipStream_t stream) {
  const float* x      = (const float*)d_in[0];
  const float* w_qkv  = (const float*)d_in[1];
  const float* w_proj = (const float*)d_in[2];
  const float* b_proj = (const float*)d_in[3];
  float* ws = (float*)d_ws;
  const size_t QSZ = (size_t)BQ * NH * NTOK * HD;   // 17,301,504 floats
  float* q  = ws;
  float* k  = ws + QSZ;
  float* v  = ws + 2 * QSZ;
  float* ao = ws + 3 * QSZ;
  float* md = ws + 4 * QSZ;                          // [b*8+h][8192][2]
  float* out0 = (float*)d_out;                       // [B][N][C]
  float* out1 = out0 + (size_t)BQ * NTOK * CDIM;     // [B][8192][256]

  qkv_gemm<<<dim3(12, 264), 256, 0, stream>>>(x, w_qkv, q, k, v);
  points_attn<<<512, 512, 0, stream>>>(q, k, v, ao, md);
  latent_attn<<<128, 256, 0, stream>>>(q, k, v, ao);
  attn_mean_k<<<1024, 256, 0, stream>>>(q, k, md, out1);
  proj_gemm<<<dim3(4, 264), 256, 0, stream>>>(ao, w_proj, b_proj, out0);
}

// Round 2
// 1499.641 us; speedup vs baseline: 1.3913x; 1.3913x over previous
//
#include <hip/hip_runtime.h>

#define BQ 4
#define NH 8
#define NTOK 8448
#define NLAT 256
#define NPTS 8192
#define CDIM 512
#define HD 64
#define SCALE 0.125f

typedef __attribute__((ext_vector_type(8))) short short8b;
typedef __attribute__((ext_vector_type(4))) float f32x4;

static __device__ __forceinline__ float4 ld4(const float* p) { return *(const float4*)p; }

static __device__ __forceinline__ short f2b(float f) {
  union { float f; unsigned u; } c; c.f = f;
  unsigned u = c.u;
  u += ((u >> 16) & 1u) + 0x7fffu;   // round-to-nearest-even
  return (short)(u >> 16);
}

static __device__ __forceinline__ short8b ldfrag(const float* p) {
  float4 x0 = ld4(p);
  float4 x1 = ld4(p + 4);
  short8b r;
  r[0] = f2b(x0.x); r[1] = f2b(x0.y); r[2] = f2b(x0.z); r[3] = f2b(x0.w);
  r[4] = f2b(x1.x); r[5] = f2b(x1.y); r[6] = f2b(x1.z); r[7] = f2b(x1.w);
  return r;
}

// ---------------- K1: qkv = x @ w_qkv^T, scatter to q,k,v laid out [b][h][n][d]
__global__ __launch_bounds__(256) void qkv_gemm(const float* __restrict__ x,
                                                const float* __restrict__ w,
                                                float* __restrict__ qo,
                                                float* __restrict__ ko,
                                                float* __restrict__ vo) {
  __shared__ float As[16][132];
  __shared__ float Bs[16][132];
  const int m0 = blockIdx.y * 128;
  const int j0 = blockIdx.x * 128;
  const int t  = threadIdx.x;
  const int tx = t & 15, ty = t >> 4;
  float acc[8][8] = {};
  for (int k0 = 0; k0 < CDIM; k0 += 16) {
#pragma unroll
    for (int i = 0; i < 2; ++i) {
      const int fl  = t + i * 256;
      const int row = fl >> 2;
      const int kq  = (fl & 3) << 2;
      float4 av = ld4(&x[(size_t)(m0 + row) * CDIM + k0 + kq]);
      As[kq + 0][row] = av.x; As[kq + 1][row] = av.y;
      As[kq + 2][row] = av.z; As[kq + 3][row] = av.w;
      float4 bv = ld4(&w[(size_t)(j0 + row) * CDIM + k0 + kq]);
      Bs[kq + 0][row] = bv.x; Bs[kq + 1][row] = bv.y;
      Bs[kq + 2][row] = bv.z; Bs[kq + 3][row] = bv.w;
    }
    __syncthreads();
#pragma unroll
    for (int kk = 0; kk < 16; ++kk) {
      float4 a0 = ld4(&As[kk][ty * 4]);
      float4 a1 = ld4(&As[kk][64 + ty * 4]);
      float4 b0 = ld4(&Bs[kk][tx * 4]);
      float4 b1 = ld4(&Bs[kk][64 + tx * 4]);
      float av[8] = {a0.x, a0.y, a0.z, a0.w, a1.x, a1.y, a1.z, a1.w};
      float bv[8] = {b0.x, b0.y, b0.z, b0.w, b1.x, b1.y, b1.z, b1.w};
#pragma unroll
      for (int i = 0; i < 8; ++i)
#pragma unroll
        for (int j = 0; j < 8; ++j) acc[i][j] += av[i] * bv[j];
    }
    __syncthreads();
  }
#pragma unroll
  for (int i = 0; i < 8; ++i) {
    const int row = m0 + ((i < 4) ? (ty * 4 + i) : (64 + ty * 4 + (i - 4)));
    const int b = row / NTOK, n = row % NTOK;
#pragma unroll
    for (int jh = 0; jh < 2; ++jh) {
      const int j = j0 + jh * 64 + tx * 4;
      const int s = j >> 9;
      const int h = (j >> 6) & 7;
      const int d = j & 63;
      float* dst = (s == 0) ? qo : ((s == 1) ? ko : vo);
      float4 val = make_float4(acc[i][jh * 4 + 0], acc[i][jh * 4 + 1],
                               acc[i][jh * 4 + 2], acc[i][jh * 4 + 3]);
      *(float4*)&dst[(((size_t)b * NH + h) * NTOK + n) * HD + d] = val;
    }
  }
}

// ---------------- K2: points attention (cross vs 256 latents + self column), online softmax
__global__ __launch_bounds__(512) void points_attn(const float* __restrict__ q,
                                                   const float* __restrict__ k,
                                                   const float* __restrict__ v,
                                                   float* __restrict__ ao,
                                                   float* __restrict__ md) {
  __shared__ float sk[256 * 64];
  __shared__ float sv[256 * 64];
  const int bid = blockIdx.x;
  const int bh = bid >> 4;      // b*8+h
  const int pt = bid & 15;
  const int t  = threadIdx.x;
  const size_t base = (size_t)bh * NTOK * HD;   // token 0 of this (b,h)
#pragma unroll
  for (int i = 0; i < 8; ++i) {
    const int c = t + i * 512;                  // float4 index in [0,4096)
    *(float4*)&sk[c * 4] = ld4(&k[base + (size_t)c * 4]);
    *(float4*)&sv[c * 4] = ld4(&v[base + (size_t)c * 4]);
  }
  const int p = pt * 512 + t;
  const size_t nb = base + (size_t)(NLAT + p) * HD;
  float qr[64];
  float sself = 0.f;
#pragma unroll
  for (int i = 0; i < 16; ++i) {
    float4 qv = ld4(&q[nb + i * 4]);
    float4 kv = ld4(&k[nb + i * 4]);
    qr[i * 4 + 0] = qv.x; qr[i * 4 + 1] = qv.y; qr[i * 4 + 2] = qv.z; qr[i * 4 + 3] = qv.w;
    sself += qv.x * kv.x + qv.y * kv.y + qv.z * kv.z + qv.w * kv.w;
  }
  sself *= SCALE;
  float acc[64];
#pragma unroll
  for (int i = 0; i < 16; ++i) {
    float4 vv = ld4(&v[nb + i * 4]);
    acc[i * 4 + 0] = vv.x; acc[i * 4 + 1] = vv.y; acc[i * 4 + 2] = vv.z; acc[i * 4 + 3] = vv.w;
  }
  float m = sself, ssum = 1.f;
  __syncthreads();
  for (int l = 0; l < 256; ++l) {
    const float* kr = &sk[l * 64];
    float s0 = 0.f, s1 = 0.f, s2 = 0.f, s3 = 0.f;
#pragma unroll
    for (int d = 0; d < 64; d += 4) {
      s0 += qr[d + 0] * kr[d + 0];
      s1 += qr[d + 1] * kr[d + 1];
      s2 += qr[d + 2] * kr[d + 2];
      s3 += qr[d + 3] * kr[d + 3];
    }
    float s = ((s0 + s1) + (s2 + s3)) * SCALE;
    const float* vr = &sv[l * 64];
    if (s <= m) {
      float pw = __expf(s - m);
      ssum += pw;
#pragma unroll
      for (int d = 0; d < 64; ++d) acc[d] += pw * vr[d];
    } else {
      float c = __expf(m - s);
      m = s;
      ssum = ssum * c + 1.f;
#pragma unroll
      for (int d = 0; d < 64; ++d) acc[d] = acc[d] * c + vr[d];
    }
  }
  const float inv = 1.f / ssum;
  const int b = bh >> 3, h = bh & 7;
  const int n = NLAT + p;
  const size_t ob = ((size_t)b * NTOK + n) * CDIM + h * HD;
#pragma unroll
  for (int i = 0; i < 16; ++i) {
    float4 ov = make_float4(acc[i * 4 + 0] * inv, acc[i * 4 + 1] * inv,
                            acc[i * 4 + 2] * inv, acc[i * 4 + 3] * inv);
    *(float4*)&ao[ob + i * 4] = ov;
  }
  md[((size_t)bh * NPTS + p) * 2 + 0] = m;
  md[((size_t)bh * NPTS + p) * 2 + 1] = ssum;
}

// ---------------- K3: latent self-attention (256x256 per (b,h))
__global__ __launch_bounds__(256) void latent_attn(const float* __restrict__ q,
                                                   const float* __restrict__ k,
                                                   const float* __restrict__ v,
                                                   float* __restrict__ ao) {
  __shared__ float sA[64 * 257];   // k staging (flat, first 16384) then probs (pitch 257)
  __shared__ float sv[256 * 64];
  __shared__ float sred[256];
  const int bid = blockIdx.x;
  const int bh = bid >> 2, rt = bid & 3;
  const int t = threadIdx.x;
  const int rl = t & 63, g = t >> 6;
  const size_t base = (size_t)bh * NTOK * HD;
#pragma unroll
  for (int i = 0; i < 16; ++i) {
    const int c = t + i * 256;     // float4 index in [0,4096)
    *(float4*)&sA[c * 4] = ld4(&k[base + (size_t)c * 4]);
    *(float4*)&sv[c * 4] = ld4(&v[base + (size_t)c * 4]);
  }
  const int r = rt * 64 + rl;
  float qr[64];
#pragma unroll
  for (int i = 0; i < 16; ++i) {
    float4 qv = ld4(&q[base + (size_t)r * HD + i * 4]);
    qr[i * 4 + 0] = qv.x; qr[i * 4 + 1] = qv.y; qr[i * 4 + 2] = qv.z; qr[i * 4 + 3] = qv.w;
  }
  __syncthreads();
  float sc[64];
  float mymax = -1e30f;
#pragma unroll
  for (int ll = 0; ll < 64; ++ll) {
    const float* kr = &sA[(g * 64 + ll) * 64];
    float s0 = 0.f, s1 = 0.f, s2 = 0.f, s3 = 0.f;
#pragma unroll
    for (int d = 0; d < 64; d += 4) {
      s0 += qr[d + 0] * kr[d + 0];
      s1 += qr[d + 1] * kr[d + 1];
      s2 += qr[d + 2] * kr[d + 2];
      s3 += qr[d + 3] * kr[d + 3];
    }
    sc[ll] = ((s0 + s1) + (s2 + s3)) * SCALE;
    mymax = fmaxf(mymax, sc[ll]);
  }
  __syncthreads();               // all k reads complete
  sred[rl * 4 + g] = mymax;
  __syncthreads();
  const float M = fmaxf(fmaxf(sred[rl * 4 + 0], sred[rl * 4 + 1]),
                        fmaxf(sred[rl * 4 + 2], sred[rl * 4 + 3]));
  __syncthreads();               // M reads done; sred reusable, sA writable
  float ps = 0.f;
#pragma unroll
  for (int ll = 0; ll < 64; ++ll) {
    float e = __expf(sc[ll] - M);
    ps += e;
    sA[rl * 257 + g * 64 + ll] = e;
  }
  sred[rl * 4 + g] = ps;
  __syncthreads();
  const float S = sred[rl * 4 + 0] + sred[rl * 4 + 1] + sred[rl * 4 + 2] + sred[rl * 4 + 3];
  const float inv = 1.f / S;
  float pacc[16] = {};
  for (int l = 0; l < 256; ++l) {
    const float pw = sA[rl * 257 + l];
    const float* vr = &sv[l * 64 + g * 16];
#pragma unroll
    for (int dd = 0; dd < 16; ++dd) pacc[dd] += pw * vr[dd];
  }
  const int b = bh >> 3, h = bh & 7;
  const size_t ob = ((size_t)b * NTOK + r) * CDIM + h * HD + g * 16;
#pragma unroll
  for (int i = 0; i < 4; ++i) {
    float4 ov = make_float4(pacc[i * 4 + 0] * inv, pacc[i * 4 + 1] * inv,
                            pacc[i * 4 + 2] * inv, pacc[i * 4 + 3] * inv);
    *(float4*)&ao[ob + i * 4] = ov;
  }
}

// ---------------- K4: attn_mean via MFMA — recompute scores from bf16 q,k; use stored m/denom.
// Block: 64 points x 256 latents, 4 waves (each wave 64x64). Loop over 8 heads,
// accumulating exp(s*scale - m)/denom into registers; write mean at the end.
__global__ __launch_bounds__(256) void attn_mean_mfma(const float* __restrict__ q,
                                                      const float* __restrict__ k,
                                                      const float* __restrict__ md,
                                                      float* __restrict__ out1) {
  const int bid = blockIdx.x;
  const int b = bid >> 7, pt = bid & 127;
  const int p0 = pt * 64;
  const int lane = threadIdx.x & 63;
  const int wave = threadIdx.x >> 6;
  const int n0 = wave * 64;
  const int lm = lane & 15, lq = lane >> 4;
  f32x4 prob[4][4] = {};   // [mt][nt], reg r = point-row subindex
  for (int h = 0; h < NH; ++h) {
    const int bh = b * NH + h;
    const size_t qbase = ((size_t)bh * NTOK + NLAT + p0) * HD;
    const size_t kbase = (size_t)bh * NTOK * HD;
    f32x4 s[4][4] = {};
#pragma unroll
    for (int kk = 0; kk < 2; ++kk) {
      const int dof = kk * 32 + lq * 8;
      short8b a[4], bb[4];
#pragma unroll
      for (int mt = 0; mt < 4; ++mt)
        a[mt] = ldfrag(q + qbase + (size_t)(mt * 16 + lm) * HD + dof);
#pragma unroll
      for (int nt = 0; nt < 4; ++nt)
        bb[nt] = ldfrag(k + kbase + (size_t)(n0 + nt * 16 + lm) * HD + dof);
#pragma unroll
      for (int mt = 0; mt < 4; ++mt)
#pragma unroll
        for (int nt = 0; nt < 4; ++nt)
          s[mt][nt] = __builtin_amdgcn_mfma_f32_16x16x32_bf16(a[mt], bb[nt], s[mt][nt], 0, 0, 0);
    }
#pragma unroll
    for (int mt = 0; mt < 4; ++mt) {
#pragma unroll
      for (int r = 0; r < 4; ++r) {
        const int p = p0 + mt * 16 + lq * 4 + r;
        const float2 mv = *(const float2*)&md[((size_t)bh * NPTS + p) * 2];
        const float mm = mv.x;
        const float inv = __builtin_amdgcn_rcpf(mv.y);
#pragma unroll
        for (int nt = 0; nt < 4; ++nt)
          prob[mt][nt][r] += __expf(fmaf(s[mt][nt][r], SCALE, -mm)) * inv;
      }
    }
  }
#pragma unroll
  for (int mt = 0; mt < 4; ++mt) {
#pragma unroll
    for (int r = 0; r < 4; ++r) {
      const int p = p0 + mt * 16 + lq * 4 + r;
      const size_t ob = ((size_t)b * NPTS + p) * NLAT;
#pragma unroll
      for (int nt = 0; nt < 4; ++nt)
        out1[ob + n0 + nt * 16 + lm] = prob[mt][nt][r] * 0.125f;
    }
  }
}

// ---------------- K5: output = ao @ w_proj^T + b_proj
__global__ __launch_bounds__(256) void proj_gemm(const float* __restrict__ A,
                                                 const float* __restrict__ w,
                                                 const float* __restrict__ bias,
                                                 float* __restrict__ out) {
  __shared__ float As[16][132];
  __shared__ float Bs[16][132];
  const int m0 = blockIdx.y * 128;
  const int j0 = blockIdx.x * 128;
  const int t  = threadIdx.x;
  const int tx = t & 15, ty = t >> 4;
  float acc[8][8] = {};
  for (int k0 = 0; k0 < CDIM; k0 += 16) {
#pragma unroll
    for (int i = 0; i < 2; ++i) {
      const int fl  = t + i * 256;
      const int row = fl >> 2;
      const int kq  = (fl & 3) << 2;
      float4 av = ld4(&A[(size_t)(m0 + row) * CDIM + k0 + kq]);
      As[kq + 0][row] = av.x; As[kq + 1][row] = av.y;
      As[kq + 2][row] = av.z; As[kq + 3][row] = av.w;
      float4 bv = ld4(&w[(size_t)(j0 + row) * CDIM + k0 + kq]);
      Bs[kq + 0][row] = bv.x; Bs[kq + 1][row] = bv.y;
      Bs[kq + 2][row] = bv.z; Bs[kq + 3][row] = bv.w;
    }
    __syncthreads();
#pragma unroll
    for (int kk = 0; kk < 16; ++kk) {
      float4 a0 = ld4(&As[kk][ty * 4]);
      float4 a1 = ld4(&As[kk][64 + ty * 4]);
      float4 b0 = ld4(&Bs[kk][tx * 4]);
      float4 b1 = ld4(&Bs[kk][64 + tx * 4]);
      float av[8] = {a0.x, a0.y, a0.z, a0.w, a1.x, a1.y, a1.z, a1.w};
      float bv[8] = {b0.x, b0.y, b0.z, b0.w, b1.x, b1.y, b1.z, b1.w};
#pragma unroll
      for (int i = 0; i < 8; ++i)
#pragma unroll
        for (int j = 0; j < 8; ++j) acc[i][j] += av[i] * bv[j];
    }
    __syncthreads();
  }
#pragma unroll
  for (int i = 0; i < 8; ++i) {
    const int row = m0 + ((i < 4) ? (ty * 4 + i) : (64 + ty * 4 + (i - 4)));
#pragma unroll
    for (int jh = 0; jh < 2; ++jh) {
      const int j = j0 + jh * 64 + tx * 4;
      float4 bb = ld4(&bias[j]);
      float4 val = make_float4(acc[i][jh * 4 + 0] + bb.x, acc[i][jh * 4 + 1] + bb.y,
                               acc[i][jh * 4 + 2] + bb.z, acc[i][jh * 4 + 3] + bb.w);
      *(float4*)&out[(size_t)row * CDIM + j] = val;
    }
  }
}

extern "C" void kernel_launch(void* const* d_in, const int* in_sizes, int n_in,
                              void* d_out, int out_size, void* d_ws, size_t ws_size,
                              hipStream_t stream) {
  const float* x      = (const float*)d_in[0];
  const float* w_qkv  = (const float*)d_in[1];
  const float* w_proj = (const float*)d_in[2];
  const float* b_proj = (const float*)d_in[3];
  float* ws = (float*)d_ws;
  const size_t QSZ = (size_t)BQ * NH * NTOK * HD;   // 17,301,504 floats
  float* q  = ws;
  float* k  = ws + QSZ;
  float* v  = ws + 2 * QSZ;
  float* ao = ws + 3 * QSZ;
  float* md = ws + 4 * QSZ;                          // [b*8+h][8192][2]
  float* out0 = (float*)d_out;                       // [B][N][C]
  float* out1 = out0 + (size_t)BQ * NTOK * CDIM;     // [B][8192][256]

  qkv_gemm<<<dim3(12, 264), 256, 0, stream>>>(x, w_qkv, q, k, v);
  points_attn<<<512, 512, 0, stream>>>(q, k, v, ao, md);
  latent_attn<<<128, 256, 0, stream>>>(q, k, v, ao);
  attn_mean_mfma<<<512, 256, 0, stream>>>(q, k, md, out1);
  proj_gemm<<<dim3(4, 264), 256, 0, stream>>>(ao, w_proj, b_proj, out0);
}

// Round 3
// 986.613 us; speedup vs baseline: 2.1148x; 1.5200x over previous
//
#include <hip/hip_runtime.h>

#define BQ 4
#define NH 8
#define NTOK 8448
#define NLAT 256
#define NPTS 8192
#define CDIM 512
#define HD 64
#define SCALE 0.125f

typedef __attribute__((ext_vector_type(8))) short short8b;
typedef __attribute__((ext_vector_type(4))) float f32x4;

static __device__ __forceinline__ float4 ld4(const float* p) { return *(const float4*)p; }

static __device__ __forceinline__ short f2b(float f) {
  union { float f; unsigned u; } c; c.f = f;
  unsigned u = c.u;
  u += ((u >> 16) & 1u) + 0x7fffu;   // round-to-nearest-even
  return (short)(u >> 16);
}

static __device__ __forceinline__ short8b ldfrag(const float* p) {
  float4 x0 = ld4(p);
  float4 x1 = ld4(p + 4);
  short8b r;
  r[0] = f2b(x0.x); r[1] = f2b(x0.y); r[2] = f2b(x0.z); r[3] = f2b(x0.w);
  r[4] = f2b(x1.x); r[5] = f2b(x1.y); r[6] = f2b(x1.z); r[7] = f2b(x1.w);
  return r;
}

static __device__ __forceinline__ void gload_lds16(const unsigned short* g, unsigned short* l) {
  __builtin_amdgcn_global_load_lds((const __attribute__((address_space(1))) void*)g,
                                   (__attribute__((address_space(3))) void*)l, 16, 0, 0);
}

// ---------------- K0: f32 -> bf16 conversion (8 elems/thread)
__global__ __launch_bounds__(256) void to_bf16(const float* __restrict__ in,
                                               unsigned short* __restrict__ out, int n8) {
  const int i = blockIdx.x * 256 + threadIdx.x;
  if (i >= n8) return;
  float4 x0 = ld4(in + (size_t)i * 8);
  float4 x1 = ld4(in + (size_t)i * 8 + 4);
  short8b r;
  r[0] = f2b(x0.x); r[1] = f2b(x0.y); r[2] = f2b(x0.z); r[3] = f2b(x0.w);
  r[4] = f2b(x1.x); r[5] = f2b(x1.y); r[6] = f2b(x1.z); r[7] = f2b(x1.w);
  *(short8b*)&out[(size_t)i * 8] = r;
}

// ---------------- K1: qkv = x @ w_qkv^T via bf16 MFMA (m97 structure), scatter to q,k,v [b][h][n][d]
__global__ __launch_bounds__(256) void qkv_mfma(const unsigned short* __restrict__ xb,
                                                const unsigned short* __restrict__ wb,
                                                float* __restrict__ qo,
                                                float* __restrict__ ko,
                                                float* __restrict__ vo) {
  __shared__ unsigned short sA[128 * 32];
  __shared__ unsigned short sB[128 * 32];
  const int m0 = blockIdx.y * 128;
  const int j0 = blockIdx.x * 128;
  const int t = threadIdx.x;
  const int lane = t & 63, wave = t >> 6;
  const int wr = wave >> 1, wc = wave & 1;
  const int lm = lane & 15, lq = lane >> 4;
  const int srow = t >> 2;            // staging row within 64-row half
  const int scol = (t & 3) * 8;       // staging col (bf16 elements)
  f32x4 acc[4][4] = {};
  for (int k0 = 0; k0 < CDIM; k0 += 32) {
    gload_lds16(xb + (size_t)(m0 + srow) * CDIM + k0 + scol, &sA[t * 8]);
    gload_lds16(xb + (size_t)(m0 + 64 + srow) * CDIM + k0 + scol, &sA[2048 + t * 8]);
    gload_lds16(wb + (size_t)(j0 + srow) * CDIM + k0 + scol, &sB[t * 8]);
    gload_lds16(wb + (size_t)(j0 + 64 + srow) * CDIM + k0 + scol, &sB[2048 + t * 8]);
    __syncthreads();
    short8b a[4], bb[4];
#pragma unroll
    for (int mt = 0; mt < 4; ++mt)
      a[mt] = *(const short8b*)&sA[(wr * 64 + mt * 16 + lm) * 32 + lq * 8];
#pragma unroll
    for (int nt = 0; nt < 4; ++nt)
      bb[nt] = *(const short8b*)&sB[(wc * 64 + nt * 16 + lm) * 32 + lq * 8];
#pragma unroll
    for (int mt = 0; mt < 4; ++mt)
#pragma unroll
      for (int nt = 0; nt < 4; ++nt)
        acc[mt][nt] = __builtin_amdgcn_mfma_f32_16x16x32_bf16(a[mt], bb[nt], acc[mt][nt], 0, 0, 0);
    __syncthreads();
  }
  const int s = j0 >> 9;
  float* dst = (s == 0) ? qo : ((s == 1) ? ko : vo);
#pragma unroll
  for (int mt = 0; mt < 4; ++mt) {
#pragma unroll
    for (int r = 0; r < 4; ++r) {
      const int m = m0 + wr * 64 + mt * 16 + lq * 4 + r;
      const int b = m / NTOK, n = m % NTOK;
#pragma unroll
      for (int nt = 0; nt < 4; ++nt) {
        const int j = j0 + wc * 64 + nt * 16 + lm;
        const int h = (j >> 6) & 7;
        const int d = j & 63;
        dst[(((size_t)b * NH + h) * NTOK + n) * HD + d] = acc[mt][nt][r];
      }
    }
  }
}

// ---------------- K2: points attention (cross vs 256 latents + self column), online softmax
__global__ __launch_bounds__(512) void points_attn(const float* __restrict__ q,
                                                   const float* __restrict__ k,
                                                   const float* __restrict__ v,
                                                   float* __restrict__ ao,
                                                   float* __restrict__ md) {
  __shared__ float sk[256 * 64];
  __shared__ float sv[256 * 64];
  const int bid = blockIdx.x;
  const int bh = bid >> 4;      // b*8+h
  const int pt = bid & 15;
  const int t  = threadIdx.x;
  const size_t base = (size_t)bh * NTOK * HD;   // token 0 of this (b,h)
#pragma unroll
  for (int i = 0; i < 8; ++i) {
    const int c = t + i * 512;                  // float4 index in [0,4096)
    *(float4*)&sk[c * 4] = ld4(&k[base + (size_t)c * 4]);
    *(float4*)&sv[c * 4] = ld4(&v[base + (size_t)c * 4]);
  }
  const int p = pt * 512 + t;
  const size_t nb = base + (size_t)(NLAT + p) * HD;
  float qr[64];
  float sself = 0.f;
#pragma unroll
  for (int i = 0; i < 16; ++i) {
    float4 qv = ld4(&q[nb + i * 4]);
    float4 kv = ld4(&k[nb + i * 4]);
    qr[i * 4 + 0] = qv.x; qr[i * 4 + 1] = qv.y; qr[i * 4 + 2] = qv.z; qr[i * 4 + 3] = qv.w;
    sself += qv.x * kv.x + qv.y * kv.y + qv.z * kv.z + qv.w * kv.w;
  }
  sself *= SCALE;
  float acc[64];
#pragma unroll
  for (int i = 0; i < 16; ++i) {
    float4 vv = ld4(&v[nb + i * 4]);
    acc[i * 4 + 0] = vv.x; acc[i * 4 + 1] = vv.y; acc[i * 4 + 2] = vv.z; acc[i * 4 + 3] = vv.w;
  }
  float m = sself, ssum = 1.f;
  __syncthreads();
  for (int l = 0; l < 256; ++l) {
    const float* kr = &sk[l * 64];
    float s0 = 0.f, s1 = 0.f, s2 = 0.f, s3 = 0.f;
#pragma unroll
    for (int d = 0; d < 64; d += 4) {
      s0 += qr[d + 0] * kr[d + 0];
      s1 += qr[d + 1] * kr[d + 1];
      s2 += qr[d + 2] * kr[d + 2];
      s3 += qr[d + 3] * kr[d + 3];
    }
    float s = ((s0 + s1) + (s2 + s3)) * SCALE;
    const float* vr = &sv[l * 64];
    if (s <= m) {
      float pw = __expf(s - m);
      ssum += pw;
#pragma unroll
      for (int d = 0; d < 64; ++d) acc[d] += pw * vr[d];
    } else {
      float c = __expf(m - s);
      m = s;
      ssum = ssum * c + 1.f;
#pragma unroll
      for (int d = 0; d < 64; ++d) acc[d] = acc[d] * c + vr[d];
    }
  }
  const float inv = 1.f / ssum;
  const int b = bh >> 3, h = bh & 7;
  const int n = NLAT + p;
  const size_t ob = ((size_t)b * NTOK + n) * CDIM + h * HD;
#pragma unroll
  for (int i = 0; i < 16; ++i) {
    float4 ov = make_float4(acc[i * 4 + 0] * inv, acc[i * 4 + 1] * inv,
                            acc[i * 4 + 2] * inv, acc[i * 4 + 3] * inv);
    *(float4*)&ao[ob + i * 4] = ov;
  }
  md[((size_t)bh * NPTS + p) * 2 + 0] = m;
  md[((size_t)bh * NPTS + p) * 2 + 1] = ssum;
}

// ---------------- K3: latent self-attention (256x256 per (b,h))
__global__ __launch_bounds__(256) void latent_attn(const float* __restrict__ q,
                                                   const float* __restrict__ k,
                                                   const float* __restrict__ v,
                                                   float* __restrict__ ao) {
  __shared__ float sA[64 * 257];   // k staging (flat, first 16384) then probs (pitch 257)
  __shared__ float sv[256 * 64];
  __shared__ float sred[256];
  const int bid = blockIdx.x;
  const int bh = bid >> 2, rt = bid & 3;
  const int t = threadIdx.x;
  const int rl = t & 63, g = t >> 6;
  const size_t base = (size_t)bh * NTOK * HD;
#pragma unroll
  for (int i = 0; i < 16; ++i) {
    const int c = t + i * 256;     // float4 index in [0,4096)
    *(float4*)&sA[c * 4] = ld4(&k[base + (size_t)c * 4]);
    *(float4*)&sv[c * 4] = ld4(&v[base + (size_t)c * 4]);
  }
  const int r = rt * 64 + rl;
  float qr[64];
#pragma unroll
  for (int i = 0; i < 16; ++i) {
    float4 qv = ld4(&q[base + (size_t)r * HD + i * 4]);
    qr[i * 4 + 0] = qv.x; qr[i * 4 + 1] = qv.y; qr[i * 4 + 2] = qv.z; qr[i * 4 + 3] = qv.w;
  }
  __syncthreads();
  float sc[64];
  float mymax = -1e30f;
#pragma unroll
  for (int ll = 0; ll < 64; ++ll) {
    const float* kr = &sA[(g * 64 + ll) * 64];
    float s0 = 0.f, s1 = 0.f, s2 = 0.f, s3 = 0.f;
#pragma unroll
    for (int d = 0; d < 64; d += 4) {
      s0 += qr[d + 0] * kr[d + 0];
      s1 += qr[d + 1] * kr[d + 1];
      s2 += qr[d + 2] * kr[d + 2];
      s3 += qr[d + 3] * kr[d + 3];
    }
    sc[ll] = ((s0 + s1) + (s2 + s3)) * SCALE;
    mymax = fmaxf(mymax, sc[ll]);
  }
  __syncthreads();               // all k reads complete
  sred[rl * 4 + g] = mymax;
  __syncthreads();
  const float M = fmaxf(fmaxf(sred[rl * 4 + 0], sred[rl * 4 + 1]),
                        fmaxf(sred[rl * 4 + 2], sred[rl * 4 + 3]));
  __syncthreads();               // M reads done; sred reusable, sA writable
  float ps = 0.f;
#pragma unroll
  for (int ll = 0; ll < 64; ++ll) {
    float e = __expf(sc[ll] - M);
    ps += e;
    sA[rl * 257 + g * 64 + ll] = e;
  }
  sred[rl * 4 + g] = ps;
  __syncthreads();
  const float S = sred[rl * 4 + 0] + sred[rl * 4 + 1] + sred[rl * 4 + 2] + sred[rl * 4 + 3];
  const float inv = 1.f / S;
  float pacc[16] = {};
  for (int l = 0; l < 256; ++l) {
    const float pw = sA[rl * 257 + l];
    const float* vr = &sv[l * 64 + g * 16];
#pragma unroll
    for (int dd = 0; dd < 16; ++dd) pacc[dd] += pw * vr[dd];
  }
  const int b = bh >> 3, h = bh & 7;
  const size_t ob = ((size_t)b * NTOK + r) * CDIM + h * HD + g * 16;
#pragma unroll
  for (int i = 0; i < 4; ++i) {
    float4 ov = make_float4(pacc[i * 4 + 0] * inv, pacc[i * 4 + 1] * inv,
                            pacc[i * 4 + 2] * inv, pacc[i * 4 + 3] * inv);
    *(float4*)&ao[ob + i * 4] = ov;
  }
}

// ---------------- K4: attn_mean via MFMA — recompute scores from bf16 q,k; use stored m/denom.
__global__ __launch_bounds__(256) void attn_mean_mfma(const float* __restrict__ q,
                                                      const float* __restrict__ k,
                                                      const float* __restrict__ md,
                                                      float* __restrict__ out1) {
  const int bid = blockIdx.x;
  const int b = bid >> 7, pt = bid & 127;
  const int p0 = pt * 64;
  const int lane = threadIdx.x & 63;
  const int wave = threadIdx.x >> 6;
  const int n0 = wave * 64;
  const int lm = lane & 15, lq = lane >> 4;
  f32x4 prob[4][4] = {};   // [mt][nt], reg r = point-row subindex
  for (int h = 0; h < NH; ++h) {
    const int bh = b * NH + h;
    const size_t qbase = ((size_t)bh * NTOK + NLAT + p0) * HD;
    const size_t kbase = (size_t)bh * NTOK * HD;
    f32x4 s[4][4] = {};
#pragma unroll
    for (int kk = 0; kk < 2; ++kk) {
      const int dof = kk * 32 + lq * 8;
      short8b a[4], bb[4];
#pragma unroll
      for (int mt = 0; mt < 4; ++mt)
        a[mt] = ldfrag(q + qbase + (size_t)(mt * 16 + lm) * HD + dof);
#pragma unroll
      for (int nt = 0; nt < 4; ++nt)
        bb[nt] = ldfrag(k + kbase + (size_t)(n0 + nt * 16 + lm) * HD + dof);
#pragma unroll
      for (int mt = 0; mt < 4; ++mt)
#pragma unroll
        for (int nt = 0; nt < 4; ++nt)
          s[mt][nt] = __builtin_amdgcn_mfma_f32_16x16x32_bf16(a[mt], bb[nt], s[mt][nt], 0, 0, 0);
    }
#pragma unroll
    for (int mt = 0; mt < 4; ++mt) {
#pragma unroll
      for (int r = 0; r < 4; ++r) {
        const int p = p0 + mt * 16 + lq * 4 + r;
        const float2 mv = *(const float2*)&md[((size_t)bh * NPTS + p) * 2];
        const float mm = mv.x;
        const float inv = __builtin_amdgcn_rcpf(mv.y);
#pragma unroll
        for (int nt = 0; nt < 4; ++nt)
          prob[mt][nt][r] += __expf(fmaf(s[mt][nt][r], SCALE, -mm)) * inv;
      }
    }
  }
#pragma unroll
  for (int mt = 0; mt < 4; ++mt) {
#pragma unroll
    for (int r = 0; r < 4; ++r) {
      const int p = p0 + mt * 16 + lq * 4 + r;
      const size_t ob = ((size_t)b * NPTS + p) * NLAT;
#pragma unroll
      for (int nt = 0; nt < 4; ++nt)
        out1[ob + n0 + nt * 16 + lm] = prob[mt][nt][r] * 0.125f;
    }
  }
}

// ---------------- K5: output = ao @ w_proj^T + b_proj
__global__ __launch_bounds__(256) void proj_gemm(const float* __restrict__ A,
                                                 const float* __restrict__ w,
                                                 const float* __restrict__ bias,
                                                 float* __restrict__ out) {
  __shared__ float As[16][132];
  __shared__ float Bs[16][132];
  const int m0 = blockIdx.y * 128;
  const int j0 = blockIdx.x * 128;
  const int t  = threadIdx.x;
  const int tx = t & 15, ty = t >> 4;
  float acc[8][8] = {};
  for (int k0 = 0; k0 < CDIM; k0 += 16) {
#pragma unroll
    for (int i = 0; i < 2; ++i) {
      const int fl  = t + i * 256;
      const int row = fl >> 2;
      const int kq  = (fl & 3) << 2;
      float4 av = ld4(&A[(size_t)(m0 + row) * CDIM + k0 + kq]);
      As[kq + 0][row] = av.x; As[kq + 1][row] = av.y;
      As[kq + 2][row] = av.z; As[kq + 3][row] = av.w;
      float4 bv = ld4(&w[(size_t)(j0 + row) * CDIM + k0 + kq]);
      Bs[kq + 0][row] = bv.x; Bs[kq + 1][row] = bv.y;
      Bs[kq + 2][row] = bv.z; Bs[kq + 3][row] = bv.w;
    }
    __syncthreads();
#pragma unroll
    for (int kk = 0; kk < 16; ++kk) {
      float4 a0 = ld4(&As[kk][ty * 4]);
      float4 a1 = ld4(&As[kk][64 + ty * 4]);
      float4 b0 = ld4(&Bs[kk][tx * 4]);
      float4 b1 = ld4(&Bs[kk][64 + tx * 4]);
      float av[8] = {a0.x, a0.y, a0.z, a0.w, a1.x, a1.y, a1.z, a1.w};
      float bv[8] = {b0.x, b0.y, b0.z, b0.w, b1.x, b1.y, b1.z, b1.w};
#pragma unroll
      for (int i = 0; i < 8; ++i)
#pragma unroll
        for (int j = 0; j < 8; ++j) acc[i][j] += av[i] * bv[j];
    }
    __syncthreads();
  }
#pragma unroll
  for (int i = 0; i < 8; ++i) {
    const int row = m0 + ((i < 4) ? (ty * 4 + i) : (64 + ty * 4 + (i - 4)));
#pragma unroll
    for (int jh = 0; jh < 2; ++jh) {
      const int j = j0 + jh * 64 + tx * 4;
      float4 bb = ld4(&bias[j]);
      float4 val = make_float4(acc[i][jh * 4 + 0] + bb.x, acc[i][jh * 4 + 1] + bb.y,
                               acc[i][jh * 4 + 2] + bb.z, acc[i][jh * 4 + 3] + bb.w);
      *(float4*)&out[(size_t)row * CDIM + j] = val;
    }
  }
}

extern "C" void kernel_launch(void* const* d_in, const int* in_sizes, int n_in,
                              void* d_out, int out_size, void* d_ws, size_t ws_size,
                              hipStream_t stream) {
  const float* x      = (const float*)d_in[0];
  const float* w_qkv  = (const float*)d_in[1];
  const float* w_proj = (const float*)d_in[2];
  const float* b_proj = (const float*)d_in[3];
  float* ws = (float*)d_ws;
  const size_t QSZ = (size_t)BQ * NH * NTOK * HD;   // 17,301,504 floats
  float* q  = ws;
  float* k  = ws + QSZ;
  float* v  = ws + 2 * QSZ;
  float* ao = ws + 3 * QSZ;
  float* md = ws + 4 * QSZ;                          // [b*8+h][8192][2]
  // bf16 staging for qkv GEMM aliases the ao region (ao written only after qkv_mfma)
  unsigned short* xb = (unsigned short*)ao;
  unsigned short* wb = xb + (size_t)BQ * NTOK * CDIM;
  float* out0 = (float*)d_out;                       // [B][N][C]
  float* out1 = out0 + (size_t)BQ * NTOK * CDIM;     // [B][8192][256]

  to_bf16<<<8448, 256, 0, stream>>>(x, xb, 2162688);
  to_bf16<<<384, 256, 0, stream>>>(w_qkv, wb, 98304);
  qkv_mfma<<<dim3(12, 264), 256, 0, stream>>>(xb, wb, q, k, v);
  points_attn<<<512, 512, 0, stream>>>(q, k, v, ao, md);
  latent_attn<<<128, 256, 0, stream>>>(q, k, v, ao);
  attn_mean_mfma<<<512, 256, 0, stream>>>(q, k, md, out1);
  proj_gemm<<<dim3(4, 264), 256, 0, stream>>>(ao, w_proj, b_proj, out0);
}

// Round 4
// 314.606 us; speedup vs baseline: 6.6321x; 3.1360x over previous
//
#include <hip/hip_runtime.h>

#define BQ 4
#define NH 8
#define NTOK 8448
#define NLAT 256
#define NPTS 8192
#define CDIM 512
#define HD 64
#define SCALE 0.125f

typedef __attribute__((ext_vector_type(8))) short short8b;
typedef __attribute__((ext_vector_type(4))) float f32x4;

static __device__ __forceinline__ float4 ld4(const float* p) { return *(const float4*)p; }

static __device__ __forceinline__ short f2b(float f) {
  union { float f; unsigned u; } c; c.f = f;
  unsigned u = c.u;
  u += ((u >> 16) & 1u) + 0x7fffu;   // round-to-nearest-even
  return (short)(u >> 16);
}

static __device__ __forceinline__ float b2f(unsigned short u) {
  union { unsigned u; float f; } c; c.u = ((unsigned)u) << 16; return c.f;
}

static __device__ __forceinline__ int cvtpk(float lo, float hi) {
  int r; asm("v_cvt_pk_bf16_f32 %0, %1, %2" : "=v"(r) : "v"(lo), "v"(hi)); return r;
}

static __device__ __forceinline__ void gload_lds16(const unsigned short* g, unsigned short* l) {
  __builtin_amdgcn_global_load_lds((const __attribute__((address_space(1))) void*)g,
                                   (__attribute__((address_space(3))) void*)l, 16, 0, 0);
}

// ---------------- K0: f32 -> bf16 conversion (8 elems/thread)
__global__ __launch_bounds__(256) void to_bf16(const float* __restrict__ in,
                                               unsigned short* __restrict__ out, int n8) {
  const int i = blockIdx.x * 256 + threadIdx.x;
  if (i >= n8) return;
  float4 x0 = ld4(in + (size_t)i * 8);
  float4 x1 = ld4(in + (size_t)i * 8 + 4);
  short8b r;
  r[0] = f2b(x0.x); r[1] = f2b(x0.y); r[2] = f2b(x0.z); r[3] = f2b(x0.w);
  r[4] = f2b(x1.x); r[5] = f2b(x1.y); r[6] = f2b(x1.z); r[7] = f2b(x1.w);
  *(short8b*)&out[(size_t)i * 8] = r;
}

// ---------------- K1: qkv = x @ w_qkv^T via bf16 MFMA, outputs bf16 q,k,v [b][h][n][d]
__global__ __launch_bounds__(256) void qkv_mfma(const unsigned short* __restrict__ xb,
                                                const unsigned short* __restrict__ wb,
                                                unsigned short* __restrict__ qo,
                                                unsigned short* __restrict__ ko,
                                                unsigned short* __restrict__ vo) {
  __shared__ unsigned short sA[128 * 32];
  __shared__ unsigned short sB[128 * 32];
  const int m0 = blockIdx.y * 128;
  const int j0 = blockIdx.x * 128;
  const int t = threadIdx.x;
  const int lane = t & 63, wave = t >> 6;
  const int wr = wave >> 1, wc = wave & 1;
  const int lm = lane & 15, lq = lane >> 4;
  const int srow = t >> 2;
  const int scol = (t & 3) * 8;
  f32x4 acc[4][4] = {};
  for (int k0 = 0; k0 < CDIM; k0 += 32) {
    gload_lds16(xb + (size_t)(m0 + srow) * CDIM + k0 + scol, &sA[t * 8]);
    gload_lds16(xb + (size_t)(m0 + 64 + srow) * CDIM + k0 + scol, &sA[2048 + t * 8]);
    gload_lds16(wb + (size_t)(j0 + srow) * CDIM + k0 + scol, &sB[t * 8]);
    gload_lds16(wb + (size_t)(j0 + 64 + srow) * CDIM + k0 + scol, &sB[2048 + t * 8]);
    __syncthreads();
    short8b a[4], bb[4];
#pragma unroll
    for (int mt = 0; mt < 4; ++mt)
      a[mt] = *(const short8b*)&sA[(wr * 64 + mt * 16 + lm) * 32 + lq * 8];
#pragma unroll
    for (int nt = 0; nt < 4; ++nt)
      bb[nt] = *(const short8b*)&sB[(wc * 64 + nt * 16 + lm) * 32 + lq * 8];
#pragma unroll
    for (int mt = 0; mt < 4; ++mt)
#pragma unroll
      for (int nt = 0; nt < 4; ++nt)
        acc[mt][nt] = __builtin_amdgcn_mfma_f32_16x16x32_bf16(a[mt], bb[nt], acc[mt][nt], 0, 0, 0);
    __syncthreads();
  }
  const int s = j0 >> 9;
  unsigned short* dst = (s == 0) ? qo : ((s == 1) ? ko : vo);
#pragma unroll
  for (int mt = 0; mt < 4; ++mt) {
#pragma unroll
    for (int r = 0; r < 4; ++r) {
      const int m = m0 + wr * 64 + mt * 16 + lq * 4 + r;
      const int b = m / NTOK, n = m % NTOK;
#pragma unroll
      for (int nt = 0; nt < 4; ++nt) {
        const int j = j0 + wc * 64 + nt * 16 + lm;
        const int h = (j >> 6) & 7;
        const int d = j & 63;
        dst[(((size_t)b * NH + h) * NTOK + n) * HD + d] = (unsigned short)f2b(acc[mt][nt][r]);
      }
    }
  }
}

// ---------------- K2: points attention via MFMA (cross vs 256 latents + exact self column)
__global__ __launch_bounds__(256) void points_attn_mfma(const unsigned short* __restrict__ qb,
                                                        const unsigned short* __restrict__ kb,
                                                        const unsigned short* __restrict__ vb,
                                                        unsigned short* __restrict__ aob,
                                                        float* __restrict__ md) {
  __shared__ unsigned short vt[64 * 264];   // V^T: vt[d][l], pitch 264 (16B-aligned rows, even bank spread)
  const int bid = blockIdx.x;
  const int bh = bid >> 6;
  const int ptile = bid & 63;
  const int t = threadIdx.x;
  const int lane = t & 63, wave = t >> 6;
  const int lm = lane & 15, lq = lane >> 4;
  const size_t bhb = (size_t)bh * NTOK * HD;
  // stage V^T (latent rows 0..255; thread t handles row t)
  {
    const unsigned short* vr = vb + bhb + (size_t)t * HD;
    short8b rv[8];
#pragma unroll
    for (int i = 0; i < 8; ++i) rv[i] = *(const short8b*)(vr + i * 8);
#pragma unroll
    for (int i = 0; i < 8; ++i)
#pragma unroll
      for (int j = 0; j < 8; ++j)
        vt[(i * 8 + j) * 264 + t] = (unsigned short)rv[i][j];
  }
  __syncthreads();
  const int pw0 = ptile * 128 + wave * 32;
  const int b = bh >> 3, h = bh & 7;
#pragma unroll
  for (int pass = 0; pass < 2; ++pass) {
    const int pp0 = pw0 + pass * 16;
    const size_t qrow = bhb + (size_t)(NLAT + pp0 + lm) * HD;
    // --- QK^T swapped: s[mt] holds S^T[latent=16mt+4lq+r][point=lm]
    f32x4 s[16] = {};
    short8b bq[2];
#pragma unroll
    for (int kd = 0; kd < 2; ++kd)
      bq[kd] = *(const short8b*)(qb + qrow + kd * 32 + lq * 8);
#pragma unroll
    for (int mt = 0; mt < 16; ++mt) {
#pragma unroll
      for (int kd = 0; kd < 2; ++kd) {
        short8b ak = *(const short8b*)(kb + bhb + (size_t)(mt * 16 + lm) * HD + kd * 32 + lq * 8);
        s[mt] = __builtin_amdgcn_mfma_f32_16x16x32_bf16(ak, bq[kd], s[mt], 0, 0, 0);
      }
    }
    // --- self score (f32 accum over bf16), split across lq quarters
    float sself = 0.f;
    {
      const unsigned short* qp = qb + qrow + lq * 16;
      const unsigned short* kp = kb + qrow + lq * 16;
      short8b q0 = *(const short8b*)qp, q1 = *(const short8b*)(qp + 8);
      short8b k0 = *(const short8b*)kp, k1 = *(const short8b*)(kp + 8);
#pragma unroll
      for (int j = 0; j < 8; ++j)
        sself += b2f((unsigned short)q0[j]) * b2f((unsigned short)k0[j]) +
                 b2f((unsigned short)q1[j]) * b2f((unsigned short)k1[j]);
    }
    sself += __shfl_xor(sself, 16);
    sself += __shfl_xor(sself, 32);
    sself *= SCALE;
    // --- softmax stats
    float mx = -1e30f;
#pragma unroll
    for (int mt = 0; mt < 16; ++mt)
#pragma unroll
      for (int r = 0; r < 4; ++r) mx = fmaxf(mx, s[mt][r]);
    mx = fmaxf(mx, __shfl_xor(mx, 16));
    mx = fmaxf(mx, __shfl_xor(mx, 32));
    const float m = fmaxf(mx * SCALE, sself);
    float sum = 0.f;
#pragma unroll
    for (int mt = 0; mt < 16; ++mt)
#pragma unroll
      for (int r = 0; r < 4; ++r) {
        float e = __expf(fmaf(s[mt][r], SCALE, -m));
        s[mt][r] = e;
        sum += e;
      }
    sum += __shfl_xor(sum, 16);
    sum += __shfl_xor(sum, 32);
    const float pself = __expf(sself - m);
    const float denom = sum + pself;
    if (lq == 0)
      *(float2*)&md[((size_t)bh * NPTS + pp0 + lm) * 2] = make_float2(m, denom);
    // --- pack P to bf16 dwords
    int pk0[16], pk1[16];
#pragma unroll
    for (int mt = 0; mt < 16; ++mt) {
      pk0[mt] = cvtpk(s[mt][0], s[mt][1]);
      pk1[mt] = cvtpk(s[mt][2], s[mt][3]);
    }
    // --- PV: redistribute P into A-frag layout via ds_bpermute, B = V^T from LDS
    const int idx0 = (((2 * lq) & 3) * 16 + lm) * 4;
    const int idx1 = (((2 * lq + 1) & 3) * 16 + lm) * 4;
    const bool hi = (lq >> 1) != 0;
    f32x4 o[4] = {};
#pragma unroll
    for (int ks = 0; ks < 8; ++ks) {
      const int mlo = 2 * ks, mhi = 2 * ks + 1;
      int d0l = __builtin_amdgcn_ds_bpermute(idx0, pk0[mlo]);
      int d0h = __builtin_amdgcn_ds_bpermute(idx0, pk0[mhi]);
      int d1l = __builtin_amdgcn_ds_bpermute(idx0, pk1[mlo]);
      int d1h = __builtin_amdgcn_ds_bpermute(idx0, pk1[mhi]);
      int d2l = __builtin_amdgcn_ds_bpermute(idx1, pk0[mlo]);
      int d2h = __builtin_amdgcn_ds_bpermute(idx1, pk0[mhi]);
      int d3l = __builtin_amdgcn_ds_bpermute(idx1, pk1[mlo]);
      int d3h = __builtin_amdgcn_ds_bpermute(idx1, pk1[mhi]);
      union { int i[4]; short8b v; } af;
      af.i[0] = hi ? d0h : d0l;
      af.i[1] = hi ? d1h : d1l;
      af.i[2] = hi ? d2h : d2l;
      af.i[3] = hi ? d3h : d3l;
#pragma unroll
      for (int ntd = 0; ntd < 4; ++ntd) {
        short8b bv = *(const short8b*)&vt[(ntd * 16 + lm) * 264 + ks * 32 + lq * 8];
        o[ntd] = __builtin_amdgcn_mfma_f32_16x16x32_bf16(af.v, bv, o[ntd], 0, 0, 0);
      }
    }
    // --- epilogue: add exact self term, normalize, write bf16 attention output
    float invd[4], psl[4];
#pragma unroll
    for (int r = 0; r < 4; ++r) {
      const int src = lq * 4 + r;
      invd[r] = 1.f / __shfl(denom, src);
      psl[r] = __shfl(pself, src);
    }
#pragma unroll
    for (int ntd = 0; ntd < 4; ++ntd) {
#pragma unroll
      for (int r = 0; r < 4; ++r) {
        const int p_ = lq * 4 + r;
        const int n = NLAT + pp0 + p_;
        const float v_ = b2f(vb[bhb + (size_t)n * HD + ntd * 16 + lm]);
        const float val = (o[ntd][r] + psl[r] * v_) * invd[r];
        aob[((size_t)b * NTOK + n) * CDIM + h * HD + ntd * 16 + lm] = (unsigned short)f2b(val);
      }
    }
  }
}

// ---------------- K3: latent self-attention (256x256 per (b,h)), bf16 in, bf16 out
__global__ __launch_bounds__(256) void latent_attn(const unsigned short* __restrict__ qb,
                                                   const unsigned short* __restrict__ kb,
                                                   const unsigned short* __restrict__ vb,
                                                   unsigned short* __restrict__ aob) {
  __shared__ float sA[64 * 257];
  __shared__ float sv[256 * 64];
  __shared__ float sred[256];
  const int bid = blockIdx.x;
  const int bh = bid >> 2, rt = bid & 3;
  const int t = threadIdx.x;
  const int rl = t & 63, g = t >> 6;
  const size_t base = (size_t)bh * NTOK * HD;
#pragma unroll
  for (int i = 0; i < 8; ++i) {
    const int c = t + i * 256;     // chunk of 8 elems, [0,2048)
    short8b kv = *(const short8b*)(kb + base + (size_t)c * 8);
    short8b vv = *(const short8b*)(vb + base + (size_t)c * 8);
#pragma unroll
    for (int j = 0; j < 8; ++j) {
      sA[c * 8 + j] = b2f((unsigned short)kv[j]);
      sv[c * 8 + j] = b2f((unsigned short)vv[j]);
    }
  }
  const int r = rt * 64 + rl;
  float qr[64];
#pragma unroll
  for (int i = 0; i < 8; ++i) {
    short8b qv = *(const short8b*)(qb + base + (size_t)r * HD + i * 8);
#pragma unroll
    for (int j = 0; j < 8; ++j) qr[i * 8 + j] = b2f((unsigned short)qv[j]);
  }
  __syncthreads();
  float sc[64];
  float mymax = -1e30f;
#pragma unroll
  for (int ll = 0; ll < 64; ++ll) {
    const float* kr = &sA[(g * 64 + ll) * 64];
    float s0 = 0.f, s1 = 0.f, s2 = 0.f, s3 = 0.f;
#pragma unroll
    for (int d = 0; d < 64; d += 4) {
      s0 += qr[d + 0] * kr[d + 0];
      s1 += qr[d + 1] * kr[d + 1];
      s2 += qr[d + 2] * kr[d + 2];
      s3 += qr[d + 3] * kr[d + 3];
    }
    sc[ll] = ((s0 + s1) + (s2 + s3)) * SCALE;
    mymax = fmaxf(mymax, sc[ll]);
  }
  __syncthreads();
  sred[rl * 4 + g] = mymax;
  __syncthreads();
  const float M = fmaxf(fmaxf(sred[rl * 4 + 0], sred[rl * 4 + 1]),
                        fmaxf(sred[rl * 4 + 2], sred[rl * 4 + 3]));
  __syncthreads();
  float ps = 0.f;
#pragma unroll
  for (int ll = 0; ll < 64; ++ll) {
    float e = __expf(sc[ll] - M);
    ps += e;
    sA[rl * 257 + g * 64 + ll] = e;
  }
  sred[rl * 4 + g] = ps;
  __syncthreads();
  const float S = sred[rl * 4 + 0] + sred[rl * 4 + 1] + sred[rl * 4 + 2] + sred[rl * 4 + 3];
  const float inv = 1.f / S;
  float pacc[16] = {};
  for (int l = 0; l < 256; ++l) {
    const float pw = sA[rl * 257 + l];
    const float* vr = &sv[l * 64 + g * 16];
#pragma unroll
    for (int dd = 0; dd < 16; ++dd) pacc[dd] += pw * vr[dd];
  }
  const int b = bh >> 3, h = bh & 7;
  const size_t ob = ((size_t)b * NTOK + r) * CDIM + h * HD + g * 16;
  union { short s[16]; short8b v[2]; } ov;
#pragma unroll
  for (int i = 0; i < 16; ++i) ov.s[i] = f2b(pacc[i] * inv);
  *(short8b*)&aob[ob] = ov.v[0];
  *(short8b*)&aob[ob + 8] = ov.v[1];
}

// ---------------- K4: attn_mean via MFMA from bf16 q,k + stored m/denom
__global__ __launch_bounds__(256) void attn_mean_mfma(const unsigned short* __restrict__ qb,
                                                      const unsigned short* __restrict__ kb,
                                                      const float* __restrict__ md,
                                                      float* __restrict__ out1) {
  const int bid = blockIdx.x;
  const int b = bid >> 7, pt = bid & 127;
  const int p0 = pt * 64;
  const int lane = threadIdx.x & 63;
  const int wave = threadIdx.x >> 6;
  const int n0 = wave * 64;
  const int lm = lane & 15, lq = lane >> 4;
  f32x4 prob[4][4] = {};
  for (int h = 0; h < NH; ++h) {
    const int bh = b * NH + h;
    const size_t qbase = ((size_t)bh * NTOK + NLAT + p0) * HD;
    const size_t kbase = (size_t)bh * NTOK * HD;
    f32x4 s[4][4] = {};
#pragma unroll
    for (int kk = 0; kk < 2; ++kk) {
      const int dof = kk * 32 + lq * 8;
      short8b a[4], bb[4];
#pragma unroll
      for (int mt = 0; mt < 4; ++mt)
        a[mt] = *(const short8b*)(qb + qbase + (size_t)(mt * 16 + lm) * HD + dof);
#pragma unroll
      for (int nt = 0; nt < 4; ++nt)
        bb[nt] = *(const short8b*)(kb + kbase + (size_t)(n0 + nt * 16 + lm) * HD + dof);
#pragma unroll
      for (int mt = 0; mt < 4; ++mt)
#pragma unroll
        for (int nt = 0; nt < 4; ++nt)
          s[mt][nt] = __builtin_amdgcn_mfma_f32_16x16x32_bf16(a[mt], bb[nt], s[mt][nt], 0, 0, 0);
    }
#pragma unroll
    for (int mt = 0; mt < 4; ++mt) {
#pragma unroll
      for (int r = 0; r < 4; ++r) {
        const int p = p0 + mt * 16 + lq * 4 + r;
        const float2 mv = *(const float2*)&md[((size_t)bh * NPTS + p) * 2];
        const float mm = mv.x;
        const float inv = __builtin_amdgcn_rcpf(mv.y);
#pragma unroll
        for (int nt = 0; nt < 4; ++nt)
          prob[mt][nt][r] += __expf(fmaf(s[mt][nt][r], SCALE, -mm)) * inv;
      }
    }
  }
#pragma unroll
  for (int mt = 0; mt < 4; ++mt) {
#pragma unroll
    for (int r = 0; r < 4; ++r) {
      const int p = p0 + mt * 16 + lq * 4 + r;
      const size_t ob = ((size_t)b * NPTS + p) * NLAT;
#pragma unroll
      for (int nt = 0; nt < 4; ++nt)
        out1[ob + n0 + nt * 16 + lm] = prob[mt][nt][r] * 0.125f;
    }
  }
}

// ---------------- K5: output = aob @ w_proj^T + b_proj via bf16 MFMA, f32 out
__global__ __launch_bounds__(256) void proj_mfma(const unsigned short* __restrict__ ab,
                                                 const unsigned short* __restrict__ wpb,
                                                 const float* __restrict__ bias,
                                                 float* __restrict__ out) {
  __shared__ unsigned short sA[128 * 32];
  __shared__ unsigned short sB[128 * 32];
  const int m0 = blockIdx.y * 128;
  const int j0 = blockIdx.x * 128;
  const int t = threadIdx.x;
  const int lane = t & 63, wave = t >> 6;
  const int wr = wave >> 1, wc = wave & 1;
  const int lm = lane & 15, lq = lane >> 4;
  const int srow = t >> 2;
  const int scol = (t & 3) * 8;
  f32x4 acc[4][4] = {};
  for (int k0 = 0; k0 < CDIM; k0 += 32) {
    gload_lds16(ab + (size_t)(m0 + srow) * CDIM + k0 + scol, &sA[t * 8]);
    gload_lds16(ab + (size_t)(m0 + 64 + srow) * CDIM + k0 + scol, &sA[2048 + t * 8]);
    gload_lds16(wpb + (size_t)(j0 + srow) * CDIM + k0 + scol, &sB[t * 8]);
    gload_lds16(wpb + (size_t)(j0 + 64 + srow) * CDIM + k0 + scol, &sB[2048 + t * 8]);
    __syncthreads();
    short8b a[4], bb[4];
#pragma unroll
    for (int mt = 0; mt < 4; ++mt)
      a[mt] = *(const short8b*)&sA[(wr * 64 + mt * 16 + lm) * 32 + lq * 8];
#pragma unroll
    for (int nt = 0; nt < 4; ++nt)
      bb[nt] = *(const short8b*)&sB[(wc * 64 + nt * 16 + lm) * 32 + lq * 8];
#pragma unroll
    for (int mt = 0; mt < 4; ++mt)
#pragma unroll
      for (int nt = 0; nt < 4; ++nt)
        acc[mt][nt] = __builtin_amdgcn_mfma_f32_16x16x32_bf16(a[mt], bb[nt], acc[mt][nt], 0, 0, 0);
    __syncthreads();
  }
#pragma unroll
  for (int mt = 0; mt < 4; ++mt) {
#pragma unroll
    for (int r = 0; r < 4; ++r) {
      const int m = m0 + wr * 64 + mt * 16 + lq * 4 + r;
#pragma unroll
      for (int nt = 0; nt < 4; ++nt) {
        const int j = j0 + wc * 64 + nt * 16 + lm;
        out[(size_t)m * CDIM + j] = acc[mt][nt][r] + bias[j];
      }
    }
  }
}

extern "C" void kernel_launch(void* const* d_in, const int* in_sizes, int n_in,
                              void* d_out, int out_size, void* d_ws, size_t ws_size,
                              hipStream_t stream) {
  const float* x      = (const float*)d_in[0];
  const float* w_qkv  = (const float*)d_in[1];
  const float* w_proj = (const float*)d_in[2];
  const float* b_proj = (const float*)d_in[3];
  const size_t QSZ = (size_t)BQ * NH * NTOK * HD;   // 17,301,504 elements
  unsigned short* qb  = (unsigned short*)d_ws;
  unsigned short* kb  = qb + QSZ;
  unsigned short* vb  = kb + QSZ;
  unsigned short* aob = vb + QSZ;
  unsigned short* xb  = aob + QSZ;                   // x bf16 (same count as aob)
  unsigned short* wb  = xb + QSZ;                    // w_qkv bf16 (786432)
  unsigned short* wpb = wb + 786432;                 // w_proj bf16 (262144)
  float* md = (float*)(wpb + 262144 + 128);          // [bh][8192][2] f32
  float* out0 = (float*)d_out;                       // [B][N][C]
  float* out1 = out0 + (size_t)BQ * NTOK * CDIM;     // [B][8192][256]

  to_bf16<<<8448, 256, 0, stream>>>(x, xb, 2162688);
  to_bf16<<<384, 256, 0, stream>>>(w_qkv, wb, 98304);
  to_bf16<<<128, 256, 0, stream>>>(w_proj, wpb, 32768);
  qkv_mfma<<<dim3(12, 264), 256, 0, stream>>>(xb, wb, qb, kb, vb);
  points_attn_mfma<<<2048, 256, 0, stream>>>(qb, kb, vb, aob, md);
  latent_attn<<<128, 256, 0, stream>>>(qb, kb, vb, aob);
  attn_mean_mfma<<<512, 256, 0, stream>>>(qb, kb, md, out1);
  proj_mfma<<<dim3(4, 264), 256, 0, stream>>>(aob, wpb, b_proj, out0);
}

// Round 5
// 287.366 us; speedup vs baseline: 7.2608x; 1.0948x over previous
//
#include <hip/hip_runtime.h>

#define BQ 4
#define NH 8
#define NTOK 8448
#define NLAT 256
#define NPTS 8192
#define CDIM 512
#define HD 64
#define SCALE 0.125f

typedef __attribute__((ext_vector_type(8))) short short8b;
typedef __attribute__((ext_vector_type(4))) float f32x4;

static __device__ __forceinline__ float4 ld4(const float* p) { return *(const float4*)p; }

static __device__ __forceinline__ short f2b(float f) {
  union { float f; unsigned u; } c; c.f = f;
  unsigned u = c.u;
  u += ((u >> 16) & 1u) + 0x7fffu;   // round-to-nearest-even
  return (short)(u >> 16);
}

static __device__ __forceinline__ float b2f(unsigned short u) {
  union { unsigned u; float f; } c; c.u = ((unsigned)u) << 16; return c.f;
}

static __device__ __forceinline__ int cvtpk(float lo, float hi) {
  int r; asm("v_cvt_pk_bf16_f32 %0, %1, %2" : "=v"(r) : "v"(lo), "v"(hi)); return r;
}

static __device__ __forceinline__ void gload_lds16(const unsigned short* g, unsigned short* l) {
  __builtin_amdgcn_global_load_lds((const __attribute__((address_space(1))) void*)g,
                                   (__attribute__((address_space(3))) void*)l, 16, 0, 0);
}

// ---------------- K0: f32 -> bf16 conversion (8 elems/thread)
__global__ __launch_bounds__(256) void to_bf16(const float* __restrict__ in,
                                               unsigned short* __restrict__ out, int n8) {
  const int i = blockIdx.x * 256 + threadIdx.x;
  if (i >= n8) return;
  float4 x0 = ld4(in + (size_t)i * 8);
  float4 x1 = ld4(in + (size_t)i * 8 + 4);
  short8b r;
  r[0] = f2b(x0.x); r[1] = f2b(x0.y); r[2] = f2b(x0.z); r[3] = f2b(x0.w);
  r[4] = f2b(x1.x); r[5] = f2b(x1.y); r[6] = f2b(x1.z); r[7] = f2b(x1.w);
  *(short8b*)&out[(size_t)i * 8] = r;
}

// ---------------- K1: qkv = x @ w_qkv^T via bf16 MFMA, outputs bf16 q,k,v [b][h][n][d]
__global__ __launch_bounds__(256) void qkv_mfma(const unsigned short* __restrict__ xb,
                                                const unsigned short* __restrict__ wb,
                                                unsigned short* __restrict__ qo,
                                                unsigned short* __restrict__ ko,
                                                unsigned short* __restrict__ vo) {
  __shared__ unsigned short sA[128 * 32];
  __shared__ unsigned short sB[128 * 32];
  // XCD-chunked bijective block swizzle (nwg = 3168 = 8*396)
  const int fl = blockIdx.y * gridDim.x + blockIdx.x;
  const int nchunk = (gridDim.x * gridDim.y) >> 3;
  const int wid = (fl & 7) * nchunk + (fl >> 3);
  const int m0 = (wid / gridDim.x) * 128;
  const int j0 = (wid % gridDim.x) * 128;
  const int t = threadIdx.x;
  const int lane = t & 63, wave = t >> 6;
  const int wr = wave >> 1, wc = wave & 1;
  const int lm = lane & 15, lq = lane >> 4;
  const int srow = t >> 2;
  const int scol = (t & 3) * 8;
  f32x4 acc[4][4] = {};
  for (int k0 = 0; k0 < CDIM; k0 += 32) {
    gload_lds16(xb + (size_t)(m0 + srow) * CDIM + k0 + scol, &sA[t * 8]);
    gload_lds16(xb + (size_t)(m0 + 64 + srow) * CDIM + k0 + scol, &sA[2048 + t * 8]);
    gload_lds16(wb + (size_t)(j0 + srow) * CDIM + k0 + scol, &sB[t * 8]);
    gload_lds16(wb + (size_t)(j0 + 64 + srow) * CDIM + k0 + scol, &sB[2048 + t * 8]);
    __syncthreads();
    short8b a[4], bb[4];
#pragma unroll
    for (int mt = 0; mt < 4; ++mt)
      a[mt] = *(const short8b*)&sA[(wr * 64 + mt * 16 + lm) * 32 + lq * 8];
#pragma unroll
    for (int nt = 0; nt < 4; ++nt)
      bb[nt] = *(const short8b*)&sB[(wc * 64 + nt * 16 + lm) * 32 + lq * 8];
#pragma unroll
    for (int mt = 0; mt < 4; ++mt)
#pragma unroll
      for (int nt = 0; nt < 4; ++nt)
        acc[mt][nt] = __builtin_amdgcn_mfma_f32_16x16x32_bf16(a[mt], bb[nt], acc[mt][nt], 0, 0, 0);
    __syncthreads();
  }
  const int s = j0 >> 9;
  unsigned short* dst = (s == 0) ? qo : ((s == 1) ? ko : vo);
#pragma unroll
  for (int mt = 0; mt < 4; ++mt) {
#pragma unroll
    for (int r = 0; r < 4; ++r) {
      const int m = m0 + wr * 64 + mt * 16 + lq * 4 + r;
      const int b = m / NTOK, n = m % NTOK;
#pragma unroll
      for (int nt = 0; nt < 4; ++nt) {
        const int j = j0 + wc * 64 + nt * 16 + lm;
        const int h = (j >> 6) & 7;
        const int d = j & 63;
        dst[(((size_t)b * NH + h) * NTOK + n) * HD + d] = (unsigned short)f2b(acc[mt][nt][r]);
      }
    }
  }
}

// ---------------- K2: points attention via MFMA — zero-shuffle PV (permuted K-row load),
// XOR-swizzled V^T, 256 points/block.
__global__ __launch_bounds__(256) void points_attn_mfma(const unsigned short* __restrict__ qb,
                                                        const unsigned short* __restrict__ kb,
                                                        const unsigned short* __restrict__ vb,
                                                        unsigned short* __restrict__ aob,
                                                        float* __restrict__ md) {
  __shared__ unsigned short vt[64 * 256];   // V^T swizzled: elem(d, l) at d*256 + ((l>>3 ^ (d&7))<<3) + (l&7)
  const int fl = blockIdx.x;
  const int wid = (fl & 7) * 128 + (fl >> 3);   // XCD-chunked (1024 = 8*128)
  const int bh = wid >> 5;
  const int ptile = wid & 31;
  const int t = threadIdx.x;
  const int lane = t & 63, wave = t >> 6;
  const int lm = lane & 15, lq = lane >> 4;
  const size_t bhb = (size_t)bh * NTOK * HD;
  // stage V^T (thread t handles latent row t)
  {
    const unsigned short* vr = vb + bhb + (size_t)t * HD;
    short8b rv[8];
#pragma unroll
    for (int i = 0; i < 8; ++i) rv[i] = *(const short8b*)(vr + i * 8);
    const int gsw = t >> 3, wi = t & 7;
#pragma unroll
    for (int d0 = 0; d0 < 8; ++d0)
#pragma unroll
      for (int j = 0; j < 8; ++j)
        vt[(d0 * 8 + j) * 256 + ((gsw ^ j) << 3) + wi] = (unsigned short)rv[d0][j];
  }
  __syncthreads();
  const int b = bh >> 3, h = bh & 7;
#pragma unroll 1
  for (int pass = 0; pass < 4; ++pass) {
    const int pp0 = ptile * 256 + wave * 64 + pass * 16;
    const size_t qrow = bhb + (size_t)(NLAT + pp0 + lm) * HD;
    const short8b bq0 = *(const short8b*)(qb + qrow + lq * 8);
    const short8b bq1 = *(const short8b*)(qb + qrow + 32 + lq * 8);
    // --- QK^T with permuted K-row addressing: lane (lm,lq) reg r of s[mt] =
    //     P[latent 32*(mt>>1) + 8*lq + 4*(mt&1) + r][point lm]
    f32x4 s[16] = {};
#pragma unroll
    for (int mt = 0; mt < 16; ++mt) {
      const int krow = ((mt >> 1) << 5) + ((lm >> 2) << 3) + ((mt & 1) << 2) + (lm & 3);
      const unsigned short* kr = kb + bhb + (size_t)krow * HD + lq * 8;
      s[mt] = __builtin_amdgcn_mfma_f32_16x16x32_bf16(*(const short8b*)kr, bq0, s[mt], 0, 0, 0);
      s[mt] = __builtin_amdgcn_mfma_f32_16x16x32_bf16(*(const short8b*)(kr + 32), bq1, s[mt], 0, 0, 0);
    }
    // --- self score (f32 accum over bf16), split across lq quarters
    float sself = 0.f;
    {
      const unsigned short* qp = qb + qrow + lq * 16;
      const unsigned short* kp = kb + qrow + lq * 16;
      short8b q0 = *(const short8b*)qp, q1 = *(const short8b*)(qp + 8);
      short8b k0 = *(const short8b*)kp, k1 = *(const short8b*)(kp + 8);
#pragma unroll
      for (int j = 0; j < 8; ++j)
        sself += b2f((unsigned short)q0[j]) * b2f((unsigned short)k0[j]) +
                 b2f((unsigned short)q1[j]) * b2f((unsigned short)k1[j]);
    }
    sself += __shfl_xor(sself, 16);
    sself += __shfl_xor(sself, 32);
    sself *= SCALE;
    // --- softmax stats
    float mx = -1e30f;
#pragma unroll
    for (int mt = 0; mt < 16; ++mt)
#pragma unroll
      for (int r = 0; r < 4; ++r) mx = fmaxf(mx, s[mt][r]);
    mx = fmaxf(mx, __shfl_xor(mx, 16));
    mx = fmaxf(mx, __shfl_xor(mx, 32));
    const float m = fmaxf(mx * SCALE, sself);
    float sum = 0.f;
#pragma unroll
    for (int mt = 0; mt < 16; ++mt)
#pragma unroll
      for (int r = 0; r < 4; ++r) {
        float e = __expf(fmaf(s[mt][r], SCALE, -m));
        s[mt][r] = e;
        sum += e;
      }
    sum += __shfl_xor(sum, 16);
    sum += __shfl_xor(sum, 32);
    const float pself = __expf(sself - m);
    const float denom = sum + pself;
    if (lq == 0)
      *(float2*)&md[((size_t)bh * NPTS + pp0 + lm) * 2] = make_float2(m, denom);
    // --- PV: A-frag comes straight from own-lane registers (zero shuffles)
    f32x4 o[4] = {};
#pragma unroll
    for (int ks = 0; ks < 8; ++ks) {
      union { int i[4]; short8b v; } af;
      af.i[0] = cvtpk(s[2 * ks][0], s[2 * ks][1]);
      af.i[1] = cvtpk(s[2 * ks][2], s[2 * ks][3]);
      af.i[2] = cvtpk(s[2 * ks + 1][0], s[2 * ks + 1][1]);
      af.i[3] = cvtpk(s[2 * ks + 1][2], s[2 * ks + 1][3]);
#pragma unroll
      for (int ntd = 0; ntd < 4; ++ntd) {
        const int row = ntd * 16 + lm;
        const short8b bv = *(const short8b*)&vt[row * 256 + ((((ks << 2) | lq) ^ (lm & 7)) << 3)];
        o[ntd] = __builtin_amdgcn_mfma_f32_16x16x32_bf16(af.v, bv, o[ntd], 0, 0, 0);
      }
    }
    // --- epilogue: exact self term, normalize, write bf16
    float invd[4], psl[4];
#pragma unroll
    for (int r = 0; r < 4; ++r) {
      const int src = lq * 4 + r;
      invd[r] = 1.f / __shfl(denom, src);
      psl[r] = __shfl(pself, src);
    }
#pragma unroll
    for (int ntd = 0; ntd < 4; ++ntd) {
#pragma unroll
      for (int r = 0; r < 4; ++r) {
        const int p_ = lq * 4 + r;
        const int n = NLAT + pp0 + p_;
        const float v_ = b2f(vb[bhb + (size_t)n * HD + ntd * 16 + lm]);
        const float val = (o[ntd][r] + psl[r] * v_) * invd[r];
        aob[((size_t)b * NTOK + n) * CDIM + h * HD + ntd * 16 + lm] = (unsigned short)f2b(val);
      }
    }
  }
}

// ---------------- K3: latent self-attention (256x256 per (b,h)), bf16 in, bf16 out
__global__ __launch_bounds__(256) void latent_attn(const unsigned short* __restrict__ qb,
                                                   const unsigned short* __restrict__ kb,
                                                   const unsigned short* __restrict__ vb,
                                                   unsigned short* __restrict__ aob) {
  __shared__ float sA[64 * 257];
  __shared__ float sv[256 * 64];
  __shared__ float sred[256];
  const int bid = blockIdx.x;
  const int bh = bid >> 2, rt = bid & 3;
  const int t = threadIdx.x;
  const int rl = t & 63, g = t >> 6;
  const size_t base = (size_t)bh * NTOK * HD;
#pragma unroll
  for (int i = 0; i < 8; ++i) {
    const int c = t + i * 256;     // chunk of 8 elems, [0,2048)
    short8b kv = *(const short8b*)(kb + base + (size_t)c * 8);
    short8b vv = *(const short8b*)(vb + base + (size_t)c * 8);
#pragma unroll
    for (int j = 0; j < 8; ++j) {
      sA[c * 8 + j] = b2f((unsigned short)kv[j]);
      sv[c * 8 + j] = b2f((unsigned short)vv[j]);
    }
  }
  const int r = rt * 64 + rl;
  float qr[64];
#pragma unroll
  for (int i = 0; i < 8; ++i) {
    short8b qv = *(const short8b*)(qb + base + (size_t)r * HD + i * 8);
#pragma unroll
    for (int j = 0; j < 8; ++j) qr[i * 8 + j] = b2f((unsigned short)qv[j]);
  }
  __syncthreads();
  float sc[64];
  float mymax = -1e30f;
#pragma unroll
  for (int ll = 0; ll < 64; ++ll) {
    const float* kr = &sA[(g * 64 + ll) * 64];
    float s0 = 0.f, s1 = 0.f, s2 = 0.f, s3 = 0.f;
#pragma unroll
    for (int d = 0; d < 64; d += 4) {
      s0 += qr[d + 0] * kr[d + 0];
      s1 += qr[d + 1] * kr[d + 1];
      s2 += qr[d + 2] * kr[d + 2];
      s3 += qr[d + 3] * kr[d + 3];
    }
    sc[ll] = ((s0 + s1) + (s2 + s3)) * SCALE;
    mymax = fmaxf(mymax, sc[ll]);
  }
  __syncthreads();
  sred[rl * 4 + g] = mymax;
  __syncthreads();
  const float M = fmaxf(fmaxf(sred[rl * 4 + 0], sred[rl * 4 + 1]),
                        fmaxf(sred[rl * 4 + 2], sred[rl * 4 + 3]));
  __syncthreads();
  float ps = 0.f;
#pragma unroll
  for (int ll = 0; ll < 64; ++ll) {
    float e = __expf(sc[ll] - M);
    ps += e;
    sA[rl * 257 + g * 64 + ll] = e;
  }
  sred[rl * 4 + g] = ps;
  __syncthreads();
  const float S = sred[rl * 4 + 0] + sred[rl * 4 + 1] + sred[rl * 4 + 2] + sred[rl * 4 + 3];
  const float inv = 1.f / S;
  float pacc[16] = {};
  for (int l = 0; l < 256; ++l) {
    const float pw = sA[rl * 257 + l];
    const float* vr = &sv[l * 64 + g * 16];
#pragma unroll
    for (int dd = 0; dd < 16; ++dd) pacc[dd] += pw * vr[dd];
  }
  const int b = bh >> 3, h = bh & 7;
  const size_t ob = ((size_t)b * NTOK + r) * CDIM + h * HD + g * 16;
  union { short s[16]; short8b v[2]; } ov;
#pragma unroll
  for (int i = 0; i < 16; ++i) ov.s[i] = f2b(pacc[i] * inv);
  *(short8b*)&aob[ob] = ov.v[0];
  *(short8b*)&aob[ob + 8] = ov.v[1];
}

// ---------------- K4: attn_mean via MFMA from bf16 q,k + stored m/denom
__global__ __launch_bounds__(256) void attn_mean_mfma(const unsigned short* __restrict__ qb,
                                                      const unsigned short* __restrict__ kb,
                                                      const float* __restrict__ md,
                                                      float* __restrict__ out1) {
  const int fl = blockIdx.x;
  const int wid = (fl & 7) * 64 + (fl >> 3);    // XCD-chunked (512 = 8*64)
  const int b = wid >> 7, pt = wid & 127;
  const int p0 = pt * 64;
  const int lane = threadIdx.x & 63;
  const int wave = threadIdx.x >> 6;
  const int n0 = wave * 64;
  const int lm = lane & 15, lq = lane >> 4;
  f32x4 prob[4][4] = {};
  for (int h = 0; h < NH; ++h) {
    const int bh = b * NH + h;
    const size_t qbase = ((size_t)bh * NTOK + NLAT + p0) * HD;
    const size_t kbase = (size_t)bh * NTOK * HD;
    f32x4 s[4][4] = {};
#pragma unroll
    for (int kk = 0; kk < 2; ++kk) {
      const int dof = kk * 32 + lq * 8;
      short8b a[4], bb[4];
#pragma unroll
      for (int mt = 0; mt < 4; ++mt)
        a[mt] = *(const short8b*)(qb + qbase + (size_t)(mt * 16 + lm) * HD + dof);
#pragma unroll
      for (int nt = 0; nt < 4; ++nt)
        bb[nt] = *(const short8b*)(kb + kbase + (size_t)(n0 + nt * 16 + lm) * HD + dof);
#pragma unroll
      for (int mt = 0; mt < 4; ++mt)
#pragma unroll
        for (int nt = 0; nt < 4; ++nt)
          s[mt][nt] = __builtin_amdgcn_mfma_f32_16x16x32_bf16(a[mt], bb[nt], s[mt][nt], 0, 0, 0);
    }
#pragma unroll
    for (int mt = 0; mt < 4; ++mt) {
#pragma unroll
      for (int r = 0; r < 4; ++r) {
        const int p = p0 + mt * 16 + lq * 4 + r;
        const float2 mv = *(const float2*)&md[((size_t)bh * NPTS + p) * 2];
        const float mm = mv.x;
        const float inv = __builtin_amdgcn_rcpf(mv.y);
#pragma unroll
        for (int nt = 0; nt < 4; ++nt)
          prob[mt][nt][r] += __expf(fmaf(s[mt][nt][r], SCALE, -mm)) * inv;
      }
    }
  }
#pragma unroll
  for (int mt = 0; mt < 4; ++mt) {
#pragma unroll
    for (int r = 0; r < 4; ++r) {
      const int p = p0 + mt * 16 + lq * 4 + r;
      const size_t ob = ((size_t)b * NPTS + p) * NLAT;
#pragma unroll
      for (int nt = 0; nt < 4; ++nt)
        out1[ob + n0 + nt * 16 + lm] = prob[mt][nt][r] * 0.125f;
    }
  }
}

// ---------------- K5: output = aob @ w_proj^T + b_proj via bf16 MFMA, f32 out
__global__ __launch_bounds__(256) void proj_mfma(const unsigned short* __restrict__ ab,
                                                 const unsigned short* __restrict__ wpb,
                                                 const float* __restrict__ bias,
                                                 float* __restrict__ out) {
  __shared__ unsigned short sA[128 * 32];
  __shared__ unsigned short sB[128 * 32];
  // XCD-chunked bijective block swizzle (nwg = 1056 = 8*132)
  const int fl = blockIdx.y * gridDim.x + blockIdx.x;
  const int nchunk = (gridDim.x * gridDim.y) >> 3;
  const int wid = (fl & 7) * nchunk + (fl >> 3);
  const int m0 = (wid / gridDim.x) * 128;
  const int j0 = (wid % gridDim.x) * 128;
  const int t = threadIdx.x;
  const int lane = t & 63, wave = t >> 6;
  const int wr = wave >> 1, wc = wave & 1;
  const int lm = lane & 15, lq = lane >> 4;
  const int srow = t >> 2;
  const int scol = (t & 3) * 8;
  f32x4 acc[4][4] = {};
  for (int k0 = 0; k0 < CDIM; k0 += 32) {
    gload_lds16(ab + (size_t)(m0 + srow) * CDIM + k0 + scol, &sA[t * 8]);
    gload_lds16(ab + (size_t)(m0 + 64 + srow) * CDIM + k0 + scol, &sA[2048 + t * 8]);
    gload_lds16(wpb + (size_t)(j0 + srow) * CDIM + k0 + scol, &sB[t * 8]);
    gload_lds16(wpb + (size_t)(j0 + 64 + srow) * CDIM + k0 + scol, &sB[2048 + t * 8]);
    __syncthreads();
    short8b a[4], bb[4];
#pragma unroll
    for (int mt = 0; mt < 4; ++mt)
      a[mt] = *(const short8b*)&sA[(wr * 64 + mt * 16 + lm) * 32 + lq * 8];
#pragma unroll
    for (int nt = 0; nt < 4; ++nt)
      bb[nt] = *(const short8b*)&sB[(wc * 64 + nt * 16 + lm) * 32 + lq * 8];
#pragma unroll
    for (int mt = 0; mt < 4; ++mt)
#pragma unroll
      for (int nt = 0; nt < 4; ++nt)
        acc[mt][nt] = __builtin_amdgcn_mfma_f32_16x16x32_bf16(a[mt], bb[nt], acc[mt][nt], 0, 0, 0);
    __syncthreads();
  }
#pragma unroll
  for (int mt = 0; mt < 4; ++mt) {
#pragma unroll
    for (int r = 0; r < 4; ++r) {
      const int m = m0 + wr * 64 + mt * 16 + lq * 4 + r;
#pragma unroll
      for (int nt = 0; nt < 4; ++nt) {
        const int j = j0 + wc * 64 + nt * 16 + lm;
        out[(size_t)m * CDIM + j] = acc[mt][nt][r] + bias[j];
      }
    }
  }
}

extern "C" void kernel_launch(void* const* d_in, const int* in_sizes, int n_in,
                              void* d_out, int out_size, void* d_ws, size_t ws_size,
                              hipStream_t stream) {
  const float* x      = (const float*)d_in[0];
  const float* w_qkv  = (const float*)d_in[1];
  const float* w_proj = (const float*)d_in[2];
  const float* b_proj = (const float*)d_in[3];
  const size_t QSZ = (size_t)BQ * NH * NTOK * HD;   // 17,301,504 elements
  unsigned short* qb  = (unsigned short*)d_ws;
  unsigned short* kb  = qb + QSZ;
  unsigned short* vb  = kb + QSZ;
  unsigned short* aob = vb + QSZ;
  unsigned short* xb  = aob + QSZ;                   // x bf16 (same count as aob)
  unsigned short* wb  = xb + QSZ;                    // w_qkv bf16 (786432)
  unsigned short* wpb = wb + 786432;                 // w_proj bf16 (262144)
  float* md = (float*)(wpb + 262144 + 128);          // [bh][8192][2] f32
  float* out0 = (float*)d_out;                       // [B][N][C]
  float* out1 = out0 + (size_t)BQ * NTOK * CDIM;     // [B][8192][256]

  to_bf16<<<8448, 256, 0, stream>>>(x, xb, 2162688);
  to_bf16<<<384, 256, 0, stream>>>(w_qkv, wb, 98304);
  to_bf16<<<128, 256, 0, stream>>>(w_proj, wpb, 32768);
  qkv_mfma<<<dim3(12, 264), 256, 0, stream>>>(xb, wb, qb, kb, vb);
  points_attn_mfma<<<1024, 256, 0, stream>>>(qb, kb, vb, aob, md);
  latent_attn<<<128, 256, 0, stream>>>(qb, kb, vb, aob);
  attn_mean_mfma<<<512, 256, 0, stream>>>(qb, kb, md, out1);
  proj_mfma<<<dim3(4, 264), 256, 0, stream>>>(aob, wpb, b_proj, out0);
}

// Round 6
// 254.539 us; speedup vs baseline: 8.1972x; 1.1290x over previous
//
#include <hip/hip_runtime.h>

#define BQ 4
#define NH 8
#define NTOK 8448
#define NLAT 256
#define NPTS 8192
#define CDIM 512
#define HD 64
#define SCALE 0.125f

typedef __attribute__((ext_vector_type(8))) short short8b;
typedef __attribute__((ext_vector_type(4))) float f32x4;

static __device__ __forceinline__ float4 ld4(const float* p) { return *(const float4*)p; }

static __device__ __forceinline__ short f2b(float f) {
  union { float f; unsigned u; } c; c.f = f;
  unsigned u = c.u;
  u += ((u >> 16) & 1u) + 0x7fffu;   // round-to-nearest-even
  return (short)(u >> 16);
}

static __device__ __forceinline__ float b2f(unsigned short u) {
  union { unsigned u; float f; } c; c.u = ((unsigned)u) << 16; return c.f;
}

static __device__ __forceinline__ int cvtpk(float lo, float hi) {
  int r; asm("v_cvt_pk_bf16_f32 %0, %1, %2" : "=v"(r) : "v"(lo), "v"(hi)); return r;
}

static __device__ __forceinline__ void gload_lds16(const unsigned short* g, unsigned short* l) {
  __builtin_amdgcn_global_load_lds((const __attribute__((address_space(1))) void*)g,
                                   (__attribute__((address_space(3))) void*)l, 16, 0, 0);
}

// ---------------- K0: fused f32 -> bf16 conversion for x, w_qkv, w_proj
__global__ __launch_bounds__(256) void to_bf16_3(const float* __restrict__ a, unsigned short* __restrict__ ao_, int na8,
                                                 const float* __restrict__ b, unsigned short* __restrict__ bo, int nb8,
                                                 const float* __restrict__ c, unsigned short* __restrict__ co, int nc8) {
  int i = blockIdx.x * 256 + threadIdx.x;
  const float* src; unsigned short* dst; int idx;
  if (i < na8) { src = a; dst = ao_; idx = i; }
  else if (i < na8 + nb8) { src = b; dst = bo; idx = i - na8; }
  else if (i < na8 + nb8 + nc8) { src = c; dst = co; idx = i - na8 - nb8; }
  else return;
  float4 x0 = ld4(src + (size_t)idx * 8);
  float4 x1 = ld4(src + (size_t)idx * 8 + 4);
  short8b r;
  r[0] = f2b(x0.x); r[1] = f2b(x0.y); r[2] = f2b(x0.z); r[3] = f2b(x0.w);
  r[4] = f2b(x1.x); r[5] = f2b(x1.y); r[6] = f2b(x1.z); r[7] = f2b(x1.w);
  *(short8b*)&dst[(size_t)idx * 8] = r;
}

// Staging macro: 128x32 bf16 tile, source-swizzled so swizzled ds_reads are ~conflict-free.
// LDS slot (row, sl) holds global col 8*(sl ^ (row&3)); reader uses sl = lq ^ (ROW&3).
#define STAGE_QKV(buf, k0, P0, P1)                                                    \
  do {                                                                                \
    gload_lds16((P0) + (size_t)(m0 + srow) * CDIM + (k0) + scol, &sA[buf][t * 8]);    \
    gload_lds16((P0) + (size_t)(m0 + 64 + srow) * CDIM + (k0) + scol, &sA[buf][2048 + t * 8]); \
    gload_lds16((P1) + (size_t)(j0 + srow) * CDIM + (k0) + scol, &sB[buf][t * 8]);    \
    gload_lds16((P1) + (size_t)(j0 + 64 + srow) * CDIM + (k0) + scol, &sB[buf][2048 + t * 8]); \
  } while (0)

// ---------------- K1: qkv = x @ w_qkv^T via bf16 MFMA (dbuf + swizzle), bf16 out [b][h][n][d]
__global__ __launch_bounds__(256) void qkv_mfma(const unsigned short* __restrict__ xb,
                                                const unsigned short* __restrict__ wb,
                                                unsigned short* __restrict__ qo,
                                                unsigned short* __restrict__ ko,
                                                unsigned short* __restrict__ vo) {
  __shared__ unsigned short sA[2][4096];
  __shared__ unsigned short sB[2][4096];
  const int fl = blockIdx.y * gridDim.x + blockIdx.x;
  const int nchunk = (gridDim.x * gridDim.y) >> 3;
  const int wid = (fl & 7) * nchunk + (fl >> 3);
  const int m0 = (wid / gridDim.x) * 128;
  const int j0 = (wid % gridDim.x) * 128;
  const int t = threadIdx.x;
  const int lane = t & 63, wave = t >> 6;
  const int wr = wave >> 1, wc = wave & 1;
  const int lm = lane & 15, lq = lane >> 4;
  const int srow = t >> 2;
  const int scol = (((t & 3) ^ ((t >> 2) & 3)) << 3);
  int offA[4], offB[4];
#pragma unroll
  for (int mt = 0; mt < 4; ++mt) {
    const int RA = wr * 64 + mt * 16 + lm;
    offA[mt] = RA * 32 + ((lq ^ (RA & 3)) << 3);
    const int RB = wc * 64 + mt * 16 + lm;
    offB[mt] = RB * 32 + ((lq ^ (RB & 3)) << 3);
  }
  f32x4 acc[4][4] = {};
  STAGE_QKV(0, 0, xb, wb);
  __syncthreads();
  int cur = 0;
  for (int k0 = 0; k0 < CDIM; k0 += 32) {
    if (k0 + 32 < CDIM) STAGE_QKV(cur ^ 1, k0 + 32, xb, wb);
    short8b a[4], bb[4];
#pragma unroll
    for (int mt = 0; mt < 4; ++mt) a[mt] = *(const short8b*)&sA[cur][offA[mt]];
#pragma unroll
    for (int nt = 0; nt < 4; ++nt) bb[nt] = *(const short8b*)&sB[cur][offB[nt]];
    __builtin_amdgcn_s_setprio(1);
#pragma unroll
    for (int mt = 0; mt < 4; ++mt)
#pragma unroll
      for (int nt = 0; nt < 4; ++nt)
        acc[mt][nt] = __builtin_amdgcn_mfma_f32_16x16x32_bf16(a[mt], bb[nt], acc[mt][nt], 0, 0, 0);
    __builtin_amdgcn_s_setprio(0);
    __syncthreads();
    cur ^= 1;
  }
  const int s = j0 >> 9;
  unsigned short* dst = (s == 0) ? qo : ((s == 1) ? ko : vo);
#pragma unroll
  for (int mt = 0; mt < 4; ++mt) {
#pragma unroll
    for (int r = 0; r < 4; ++r) {
      const int m = m0 + wr * 64 + mt * 16 + lq * 4 + r;
      const int b = m / NTOK, n = m % NTOK;
#pragma unroll
      for (int nt = 0; nt < 4; ++nt) {
        const int j = j0 + wc * 64 + nt * 16 + lm;
        const int h = (j >> 6) & 7;
        const int d = j & 63;
        dst[(((size_t)b * NH + h) * NTOK + n) * HD + d] = (unsigned short)f2b(acc[mt][nt][r]);
      }
    }
  }
}

// ---------------- K2: points attention via MFMA — zero-shuffle PV, XOR-swizzled V^T
__global__ __launch_bounds__(256) void points_attn_mfma(const unsigned short* __restrict__ qb,
                                                        const unsigned short* __restrict__ kb,
                                                        const unsigned short* __restrict__ vb,
                                                        unsigned short* __restrict__ aob,
                                                        float* __restrict__ md) {
  __shared__ unsigned short vt[64 * 256];   // V^T swizzled: elem(d,l) at d*256 + ((l>>3 ^ (d&7))<<3) + (l&7)
  const int fl = blockIdx.x;
  const int wid = (fl & 7) * 128 + (fl >> 3);   // XCD-chunked (1024 = 8*128)
  const int bh = wid >> 5;
  const int ptile = wid & 31;
  const int t = threadIdx.x;
  const int lane = t & 63, wave = t >> 6;
  const int lm = lane & 15, lq = lane >> 4;
  const size_t bhb = (size_t)bh * NTOK * HD;
  {
    const unsigned short* vr = vb + bhb + (size_t)t * HD;
    short8b rv[8];
#pragma unroll
    for (int i = 0; i < 8; ++i) rv[i] = *(const short8b*)(vr + i * 8);
    const int gsw = t >> 3, wi = t & 7;
#pragma unroll
    for (int d0 = 0; d0 < 8; ++d0)
#pragma unroll
      for (int j = 0; j < 8; ++j)
        vt[(d0 * 8 + j) * 256 + ((gsw ^ j) << 3) + wi] = (unsigned short)rv[d0][j];
  }
  __syncthreads();
  const int b = bh >> 3, h = bh & 7;
#pragma unroll 1
  for (int pass = 0; pass < 4; ++pass) {
    const int pp0 = ptile * 256 + wave * 64 + pass * 16;
    const size_t qrow = bhb + (size_t)(NLAT + pp0 + lm) * HD;
    const short8b bq0 = *(const short8b*)(qb + qrow + lq * 8);
    const short8b bq1 = *(const short8b*)(qb + qrow + 32 + lq * 8);
    f32x4 s[16] = {};
    __builtin_amdgcn_s_setprio(1);
#pragma unroll
    for (int mt = 0; mt < 16; ++mt) {
      const int krow = ((mt >> 1) << 5) + ((lm >> 2) << 3) + ((mt & 1) << 2) + (lm & 3);
      const unsigned short* kr = kb + bhb + (size_t)krow * HD + lq * 8;
      s[mt] = __builtin_amdgcn_mfma_f32_16x16x32_bf16(*(const short8b*)kr, bq0, s[mt], 0, 0, 0);
      s[mt] = __builtin_amdgcn_mfma_f32_16x16x32_bf16(*(const short8b*)(kr + 32), bq1, s[mt], 0, 0, 0);
    }
    __builtin_amdgcn_s_setprio(0);
    float sself = 0.f;
    {
      const unsigned short* qp = qb + qrow + lq * 16;
      const unsigned short* kp = kb + qrow + lq * 16;
      short8b q0 = *(const short8b*)qp, q1 = *(const short8b*)(qp + 8);
      short8b k0 = *(const short8b*)kp, k1 = *(const short8b*)(kp + 8);
#pragma unroll
      for (int j = 0; j < 8; ++j)
        sself += b2f((unsigned short)q0[j]) * b2f((unsigned short)k0[j]) +
                 b2f((unsigned short)q1[j]) * b2f((unsigned short)k1[j]);
    }
    sself += __shfl_xor(sself, 16);
    sself += __shfl_xor(sself, 32);
    sself *= SCALE;
    float mx = -1e30f;
#pragma unroll
    for (int mt = 0; mt < 16; ++mt)
#pragma unroll
      for (int r = 0; r < 4; ++r) mx = fmaxf(mx, s[mt][r]);
    mx = fmaxf(mx, __shfl_xor(mx, 16));
    mx = fmaxf(mx, __shfl_xor(mx, 32));
    const float m = fmaxf(mx * SCALE, sself);
    float sum = 0.f;
#pragma unroll
    for (int mt = 0; mt < 16; ++mt)
#pragma unroll
      for (int r = 0; r < 4; ++r) {
        float e = __expf(fmaf(s[mt][r], SCALE, -m));
        s[mt][r] = e;
        sum += e;
      }
    sum += __shfl_xor(sum, 16);
    sum += __shfl_xor(sum, 32);
    const float pself = __expf(sself - m);
    const float denom = sum + pself;
    if (lq == 0)
      *(float2*)&md[((size_t)bh * NPTS + pp0 + lm) * 2] = make_float2(m, denom);
    f32x4 o[4] = {};
    __builtin_amdgcn_s_setprio(1);
#pragma unroll
    for (int ks = 0; ks < 8; ++ks) {
      union { int i[4]; short8b v; } af;
      af.i[0] = cvtpk(s[2 * ks][0], s[2 * ks][1]);
      af.i[1] = cvtpk(s[2 * ks][2], s[2 * ks][3]);
      af.i[2] = cvtpk(s[2 * ks + 1][0], s[2 * ks + 1][1]);
      af.i[3] = cvtpk(s[2 * ks + 1][2], s[2 * ks + 1][3]);
#pragma unroll
      for (int ntd = 0; ntd < 4; ++ntd) {
        const int row = ntd * 16 + lm;
        const short8b bv = *(const short8b*)&vt[row * 256 + ((((ks << 2) | lq) ^ (lm & 7)) << 3)];
        o[ntd] = __builtin_amdgcn_mfma_f32_16x16x32_bf16(af.v, bv, o[ntd], 0, 0, 0);
      }
    }
    __builtin_amdgcn_s_setprio(0);
    float invd[4], psl[4];
#pragma unroll
    for (int r = 0; r < 4; ++r) {
      const int src = lq * 4 + r;
      invd[r] = 1.f / __shfl(denom, src);
      psl[r] = __shfl(pself, src);
    }
#pragma unroll
    for (int ntd = 0; ntd < 4; ++ntd) {
#pragma unroll
      for (int r = 0; r < 4; ++r) {
        const int p_ = lq * 4 + r;
        const int n = NLAT + pp0 + p_;
        const float v_ = b2f(vb[bhb + (size_t)n * HD + ntd * 16 + lm]);
        const float val = (o[ntd][r] + psl[r] * v_) * invd[r];
        aob[((size_t)b * NTOK + n) * CDIM + h * HD + ntd * 16 + lm] = (unsigned short)f2b(val);
      }
    }
  }
}

// ---------------- K3: latent self-attention via MFMA (same machinery, no self column)
__global__ __launch_bounds__(256) void latent_mfma(const unsigned short* __restrict__ qb,
                                                   const unsigned short* __restrict__ kb,
                                                   const unsigned short* __restrict__ vb,
                                                   unsigned short* __restrict__ aob) {
  __shared__ unsigned short vt[64 * 256];
  const int fl = blockIdx.x;
  const int wid = (fl & 7) * 16 + (fl >> 3);    // XCD-chunked (128 = 8*16)
  const int bh = wid >> 2;
  const int qt = wid & 3;
  const int t = threadIdx.x;
  const int lane = t & 63, wave = t >> 6;
  const int lm = lane & 15, lq = lane >> 4;
  const size_t bhb = (size_t)bh * NTOK * HD;
  {
    const unsigned short* vr = vb + bhb + (size_t)t * HD;
    short8b rv[8];
#pragma unroll
    for (int i = 0; i < 8; ++i) rv[i] = *(const short8b*)(vr + i * 8);
    const int gsw = t >> 3, wi = t & 7;
#pragma unroll
    for (int d0 = 0; d0 < 8; ++d0)
#pragma unroll
      for (int j = 0; j < 8; ++j)
        vt[(d0 * 8 + j) * 256 + ((gsw ^ j) << 3) + wi] = (unsigned short)rv[d0][j];
  }
  __syncthreads();
  const int b = bh >> 3, h = bh & 7;
  const int q0 = qt * 64 + wave * 16;
  const size_t qrow = bhb + (size_t)(q0 + lm) * HD;
  const short8b bq0 = *(const short8b*)(qb + qrow + lq * 8);
  const short8b bq1 = *(const short8b*)(qb + qrow + 32 + lq * 8);
  f32x4 s[16] = {};
  __builtin_amdgcn_s_setprio(1);
#pragma unroll
  for (int mt = 0; mt < 16; ++mt) {
    const int krow = ((mt >> 1) << 5) + ((lm >> 2) << 3) + ((mt & 1) << 2) + (lm & 3);
    const unsigned short* kr = kb + bhb + (size_t)krow * HD + lq * 8;
    s[mt] = __builtin_amdgcn_mfma_f32_16x16x32_bf16(*(const short8b*)kr, bq0, s[mt], 0, 0, 0);
    s[mt] = __builtin_amdgcn_mfma_f32_16x16x32_bf16(*(const short8b*)(kr + 32), bq1, s[mt], 0, 0, 0);
  }
  __builtin_amdgcn_s_setprio(0);
  float mx = -1e30f;
#pragma unroll
  for (int mt = 0; mt < 16; ++mt)
#pragma unroll
    for (int r = 0; r < 4; ++r) mx = fmaxf(mx, s[mt][r]);
  mx = fmaxf(mx, __shfl_xor(mx, 16));
  mx = fmaxf(mx, __shfl_xor(mx, 32));
  const float m = mx * SCALE;
  float sum = 0.f;
#pragma unroll
  for (int mt = 0; mt < 16; ++mt)
#pragma unroll
    for (int r = 0; r < 4; ++r) {
      float e = __expf(fmaf(s[mt][r], SCALE, -m));
      s[mt][r] = e;
      sum += e;
    }
  sum += __shfl_xor(sum, 16);
  sum += __shfl_xor(sum, 32);
  const float denom = sum;
  f32x4 o[4] = {};
  __builtin_amdgcn_s_setprio(1);
#pragma unroll
  for (int ks = 0; ks < 8; ++ks) {
    union { int i[4]; short8b v; } af;
    af.i[0] = cvtpk(s[2 * ks][0], s[2 * ks][1]);
    af.i[1] = cvtpk(s[2 * ks][2], s[2 * ks][3]);
    af.i[2] = cvtpk(s[2 * ks + 1][0], s[2 * ks + 1][1]);
    af.i[3] = cvtpk(s[2 * ks + 1][2], s[2 * ks + 1][3]);
#pragma unroll
    for (int ntd = 0; ntd < 4; ++ntd) {
      const int row = ntd * 16 + lm;
      const short8b bv = *(const short8b*)&vt[row * 256 + ((((ks << 2) | lq) ^ (lm & 7)) << 3)];
      o[ntd] = __builtin_amdgcn_mfma_f32_16x16x32_bf16(af.v, bv, o[ntd], 0, 0, 0);
    }
  }
  __builtin_amdgcn_s_setprio(0);
  float invd[4];
#pragma unroll
  for (int r = 0; r < 4; ++r) invd[r] = 1.f / __shfl(denom, lq * 4 + r);
#pragma unroll
  for (int ntd = 0; ntd < 4; ++ntd) {
#pragma unroll
    for (int r = 0; r < 4; ++r) {
      const int n = q0 + lq * 4 + r;
      aob[((size_t)b * NTOK + n) * CDIM + h * HD + ntd * 16 + lm] =
          (unsigned short)f2b(o[ntd][r] * invd[r]);
    }
  }
}

// ---------------- K4: attn_mean via MFMA from bf16 q,k + stored m/denom
__global__ __launch_bounds__(256) void attn_mean_mfma(const unsigned short* __restrict__ qb,
                                                      const unsigned short* __restrict__ kb,
                                                      const float* __restrict__ md,
                                                      float* __restrict__ out1) {
  const int fl = blockIdx.x;
  const int wid = (fl & 7) * 64 + (fl >> 3);    // XCD-chunked (512 = 8*64)
  const int b = wid >> 7, pt = wid & 127;
  const int p0 = pt * 64;
  const int lane = threadIdx.x & 63;
  const int wave = threadIdx.x >> 6;
  const int n0 = wave * 64;
  const int lm = lane & 15, lq = lane >> 4;
  f32x4 prob[4][4] = {};
  for (int h = 0; h < NH; ++h) {
    const int bh = b * NH + h;
    const size_t qbase = ((size_t)bh * NTOK + NLAT + p0) * HD;
    const size_t kbase = (size_t)bh * NTOK * HD;
    f32x4 s[4][4] = {};
    __builtin_amdgcn_s_setprio(1);
#pragma unroll
    for (int kk = 0; kk < 2; ++kk) {
      const int dof = kk * 32 + lq * 8;
      short8b a[4], bb[4];
#pragma unroll
      for (int mt = 0; mt < 4; ++mt)
        a[mt] = *(const short8b*)(qb + qbase + (size_t)(mt * 16 + lm) * HD + dof);
#pragma unroll
      for (int nt = 0; nt < 4; ++nt)
        bb[nt] = *(const short8b*)(kb + kbase + (size_t)(n0 + nt * 16 + lm) * HD + dof);
#pragma unroll
      for (int mt = 0; mt < 4; ++mt)
#pragma unroll
        for (int nt = 0; nt < 4; ++nt)
          s[mt][nt] = __builtin_amdgcn_mfma_f32_16x16x32_bf16(a[mt], bb[nt], s[mt][nt], 0, 0, 0);
    }
    __builtin_amdgcn_s_setprio(0);
#pragma unroll
    for (int mt = 0; mt < 4; ++mt) {
#pragma unroll
      for (int r = 0; r < 4; ++r) {
        const int p = p0 + mt * 16 + lq * 4 + r;
        const float2 mv = *(const float2*)&md[((size_t)bh * NPTS + p) * 2];
        const float mm = mv.x;
        const float inv = __builtin_amdgcn_rcpf(mv.y);
#pragma unroll
        for (int nt = 0; nt < 4; ++nt)
          prob[mt][nt][r] += __expf(fmaf(s[mt][nt][r], SCALE, -mm)) * inv;
      }
    }
  }
#pragma unroll
  for (int mt = 0; mt < 4; ++mt) {
#pragma unroll
    for (int r = 0; r < 4; ++r) {
      const int p = p0 + mt * 16 + lq * 4 + r;
      const size_t ob = ((size_t)b * NPTS + p) * NLAT;
#pragma unroll
      for (int nt = 0; nt < 4; ++nt)
        out1[ob + n0 + nt * 16 + lm] = prob[mt][nt][r] * 0.125f;
    }
  }
}

// ---------------- K5: output = aob @ w_proj^T + b_proj via bf16 MFMA (dbuf + swizzle), f32 out
__global__ __launch_bounds__(256) void proj_mfma(const unsigned short* __restrict__ ab,
                                                 const unsigned short* __restrict__ wpb,
                                                 const float* __restrict__ bias,
                                                 float* __restrict__ out) {
  __shared__ unsigned short sA[2][4096];
  __shared__ unsigned short sB[2][4096];
  const int fl = blockIdx.y * gridDim.x + blockIdx.x;
  const int nchunk = (gridDim.x * gridDim.y) >> 3;
  const int wid = (fl & 7) * nchunk + (fl >> 3);
  const int m0 = (wid / gridDim.x) * 128;
  const int j0 = (wid % gridDim.x) * 128;
  const int t = threadIdx.x;
  const int lane = t & 63, wave = t >> 6;
  const int wr = wave >> 1, wc = wave & 1;
  const int lm = lane & 15, lq = lane >> 4;
  const int srow = t >> 2;
  const int scol = (((t & 3) ^ ((t >> 2) & 3)) << 3);
  int offA[4], offB[4];
#pragma unroll
  for (int mt = 0; mt < 4; ++mt) {
    const int RA = wr * 64 + mt * 16 + lm;
    offA[mt] = RA * 32 + ((lq ^ (RA & 3)) << 3);
    const int RB = wc * 64 + mt * 16 + lm;
    offB[mt] = RB * 32 + ((lq ^ (RB & 3)) << 3);
  }
  f32x4 acc[4][4] = {};
  STAGE_QKV(0, 0, ab, wpb);
  __syncthreads();
  int cur = 0;
  for (int k0 = 0; k0 < CDIM; k0 += 32) {
    if (k0 + 32 < CDIM) STAGE_QKV(cur ^ 1, k0 + 32, ab, wpb);
    short8b a[4], bb[4];
#pragma unroll
    for (int mt = 0; mt < 4; ++mt) a[mt] = *(const short8b*)&sA[cur][offA[mt]];
#pragma unroll
    for (int nt = 0; nt < 4; ++nt) bb[nt] = *(const short8b*)&sB[cur][offB[nt]];
    __builtin_amdgcn_s_setprio(1);
#pragma unroll
    for (int mt = 0; mt < 4; ++mt)
#pragma unroll
      for (int nt = 0; nt < 4; ++nt)
        acc[mt][nt] = __builtin_amdgcn_mfma_f32_16x16x32_bf16(a[mt], bb[nt], acc[mt][nt], 0, 0, 0);
    __builtin_amdgcn_s_setprio(0);
    __syncthreads();
    cur ^= 1;
  }
#pragma unroll
  for (int mt = 0; mt < 4; ++mt) {
#pragma unroll
    for (int r = 0; r < 4; ++r) {
      const int m = m0 + wr * 64 + mt * 16 + lq * 4 + r;
#pragma unroll
      for (int nt = 0; nt < 4; ++nt) {
        const int j = j0 + wc * 64 + nt * 16 + lm;
        out[(size_t)m * CDIM + j] = acc[mt][nt][r] + bias[j];
      }
    }
  }
}

extern "C" void kernel_launch(void* const* d_in, const int* in_sizes, int n_in,
                              void* d_out, int out_size, void* d_ws, size_t ws_size,
                              hipStream_t stream) {
  const float* x      = (const float*)d_in[0];
  const float* w_qkv  = (const float*)d_in[1];
  const float* w_proj = (const float*)d_in[2];
  const float* b_proj = (const float*)d_in[3];
  const size_t QSZ = (size_t)BQ * NH * NTOK * HD;   // 17,301,504 elements
  unsigned short* qb  = (unsigned short*)d_ws;
  unsigned short* kb  = qb + QSZ;
  unsigned short* vb  = kb + QSZ;
  unsigned short* aob = vb + QSZ;
  unsigned short* xb  = aob + QSZ;                   // x bf16 (same count as aob)
  unsigned short* wb  = xb + QSZ;                    // w_qkv bf16 (786432)
  unsigned short* wpb = wb + 786432;                 // w_proj bf16 (262144)
  float* md = (float*)(wpb + 262144 + 128);          // [bh][8192][2] f32
  float* out0 = (float*)d_out;                       // [B][N][C]
  float* out1 = out0 + (size_t)BQ * NTOK * CDIM;     // [B][8192][256]

  to_bf16_3<<<8960, 256, 0, stream>>>(x, xb, 2162688, w_qkv, wb, 98304, w_proj, wpb, 32768);
  qkv_mfma<<<dim3(12, 264), 256, 0, stream>>>(xb, wb, qb, kb, vb);
  points_attn_mfma<<<1024, 256, 0, stream>>>(qb, kb, vb, aob, md);
  latent_mfma<<<128, 256, 0, stream>>>(qb, kb, vb, aob);
  attn_mean_mfma<<<512, 256, 0, stream>>>(qb, kb, md, out1);
  proj_mfma<<<dim3(4, 264), 256, 0, stream>>>(aob, wpb, b_proj, out0);
}